// Round 24
// baseline (319.953 us; speedup 1.0000x reference)
//
#include <hip/hip_runtime.h>
#include <hip/hip_bf16.h>

typedef __attribute__((ext_vector_type(8))) short short8;
typedef __attribute__((ext_vector_type(4))) float f32x4;
typedef __attribute__((ext_vector_type(4))) unsigned short ushort4_t;

#define BSZ 4
#define LSEQ 1024
#define CCH 512
#define BL (BSZ*LSEQ)   // 4096 rows
#define BL2 (2*BL)      // both directions batched: 8192 rows
#define DI 1024         // d_inner
#define NST 16
#define DTR 32
#define NCH 32          // scan chunks
#define CLEN 32         // chunk length (NCH*CLEN == LSEQ)

__device__ __forceinline__ float sigmoidf_(float x){ return 1.f/(1.f+__expf(-x)); }
// fast softplus: v_exp + add + v_log -- the OCML log1pf path is ~30 VALU inst (R14 lesson)
__device__ __forceinline__ float softplus_(float x){ return x > 20.f ? x : __logf(1.f + __expf(x)); }
__device__ __forceinline__ float fexp2_(float x){ return __builtin_amdgcn_exp2f(x); }  // raw v_exp_f32
__device__ __forceinline__ unsigned short f2bf_(float f){
  __hip_bfloat16 h = __float2bfloat16(f); return *(unsigned short*)&h;
}
__device__ __forceinline__ float b2f_(unsigned short s){
  unsigned u = ((unsigned)s) << 16; float f; __builtin_memcpy(&f, &u, 4); return f;
}

typedef const __attribute__((address_space(1))) unsigned int* gas_t;
typedef __attribute__((address_space(3))) unsigned int* las_t;
__device__ __forceinline__ void gload16(const void* g, void* l){
  __builtin_amdgcn_global_load_lds((gas_t)g, (las_t)l, 16, 0, 0);
}

// ---------------- prep / elementwise kernels ----------------

// all 9 f32->bf16 weight casts in ONE launch (region table in kernarg)
struct CastEnt { const float* s; unsigned short* d; unsigned n4, acc; };
struct CastArgs { CastEnt e[9]; unsigned total4; };
__global__ void k_cast_all(CastArgs a){
  unsigned i = blockIdx.x*256 + threadIdx.x;
  if (i >= a.total4) return;
  #pragma unroll
  for (int k=0;k<9;k++){
    if (i < a.e[k].acc + a.e[k].n4){
      unsigned j = i - a.e[k].acc;
      float4 v = ((const float4*)a.e[k].s)[j];
      ushort4_t o = { f2bf_(v.x), f2bf_(v.y), f2bf_(v.z), f2bf_(v.w) };
      *(ushort4_t*)(a.e[k].d + (size_t)j*4) = o;
      return;
    }
  }
}

// conv_w [3][512][512][5] -> wt [3][512][2560], j = k*512 + ci  (matches contiguous patch)
__global__ void k_prep_convw(const float* __restrict__ cw, __hip_bfloat16* __restrict__ wt){
  int i = blockIdx.x*256 + threadIdx.x;
  const int total = 3*CCH*CCH*5;
  if (i >= total) return;
  int j = i % (CCH*5);
  int co = (i/(CCH*5)) % CCH;
  int layer = i/(CCH*5*CCH);
  int k = j >> 9, ci = j & 511;
  wt[i] = __float2bfloat16(cw[(((size_t)layer*CCH + co)*CCH + ci)*5 + k]);
}

// gather emb[x] into padded [B][L+4][C] bf16; tail range zeroes xpad1's 4 pad rows
__global__ void k_embed(const int* __restrict__ x, const float* __restrict__ emb,
                        __hip_bfloat16* __restrict__ xpad0, __hip_bfloat16* __restrict__ xpad1){
  int i = blockIdx.x*256 + threadIdx.x;
  const int total = BSZ*(LSEQ+4)*CCH;
  const int total2 = total + BSZ*4*CCH;
  if (i >= total2) return;
  if (i >= total){
    int j = i - total;
    int c = j & (CCH-1);
    int pr = (j >> 9) & 3;
    int b = j >> 11;
    int rr = (pr < 2) ? pr : (LSEQ+2) + (pr-2);
    xpad1[((size_t)b*(LSEQ+4) + rr)*CCH + c] = __float2bfloat16(0.f);
    return;
  }
  int c = i & (CCH-1);
  int r = (i >> 9) % (LSEQ+4);
  int b = i / ((LSEQ+4)*CCH);
  float v = 0.f;
  if (r >= 2 && r < LSEQ+2){
    int tok = x[b*LSEQ + (r-2)];
    v = emb[(size_t)tok*CCH + c];
  }
  xpad0[i] = __float2bfloat16(v);
}

// per-(b,l) channel LayerNorm over bf16 (p0+p1+p2+p3) + scale/shift + LeakyReLU(0.2) + mask
__global__ __launch_bounds__(256) void k_ln(
    const unsigned short* __restrict__ p0, const unsigned short* __restrict__ p1,
    const unsigned short* __restrict__ p2, const unsigned short* __restrict__ p3,
    const float* __restrict__ g, const float* __restrict__ bb,
    const unsigned char* __restrict__ mask,
    __hip_bfloat16* __restrict__ xpad_next,
    __hip_bfloat16* __restrict__ h_enc){
  int row = blockIdx.x;                 // b*1024 + l
  int b = row >> 10, l = row & 1023;
  size_t ro = (size_t)row*CCH;
  int t = threadIdx.x;
  float v0 = b2f_(p0[ro+t]) + b2f_(p1[ro+t]) + b2f_(p2[ro+t]) + b2f_(p3[ro+t]);
  float v1 = b2f_(p0[ro+t+256]) + b2f_(p1[ro+t+256]) + b2f_(p2[ro+t+256]) + b2f_(p3[ro+t+256]);
  float s = v0+v1, s2 = v0*v0 + v1*v1;
  #pragma unroll
  for (int off=32; off>0; off>>=1){ s += __shfl_down(s,off); s2 += __shfl_down(s2,off); }
  __shared__ float ls[8];
  if ((t&63)==0){ ls[t>>6] = s; ls[(t>>6)+4] = s2; }
  __syncthreads();
  float S  = ls[0]+ls[1]+ls[2]+ls[3];
  float S2 = ls[4]+ls[5]+ls[6]+ls[7];
  float mu = S*(1.f/CCH);
  float var = S2*(1.f/CCH) - mu*mu;
  float rs = rsqrtf(var + 1e-5f);
  bool mk = mask[row] != 0;
  #pragma unroll
  for (int e=0; e<2; e++){
    int c = t + e*256;
    float v = e ? v1 : v0;
    float h = (v-mu)*rs*g[c] + bb[c];
    h = h > 0.f ? h : 0.2f*h;
    if (mk) h = 0.f;
    __hip_bfloat16 hb = __float2bfloat16(h);
    if (xpad_next) xpad_next[((size_t)b*(LSEQ+4) + (l+2))*CCH + c] = hb;
    if (h_enc) h_enc[(size_t)row*CCH + c] = hb;
  }
}

// ---------------- K-split GEMM for skinny N=64 (x_proj), batched dirs ----------------
// 16 rows per block; 4 waves each own a K/4 slice; LDS reduce.
__global__ __launch_bounds__(256) void k_gemm_ksplit(
    const __hip_bfloat16* __restrict__ A, int lda,
    const __hip_bfloat16* __restrict__ W, size_t wStride,
    float* __restrict__ Cout, int ldc, int K, unsigned short* __restrict__ dtb){
  __shared__ float red[4*1024];   // 16 KB
  int m0 = blockIdx.x << 4;
  const __hip_bfloat16* Wd = W + (size_t)(m0 >> 12)*wStride;
  int tid = threadIdx.x;
  int w = tid >> 6, lane = tid & 63;
  int r = lane & 15, kg = lane >> 4;
  int Kw = K >> 2;
  int kbase = w*Kw;

  const short* Ap = (const short*)A + (size_t)(m0 + r)*lda + kbase + kg*8;
  const short* Wp[4];
  #pragma unroll
  for (int nj=0; nj<4; nj++)
    Wp[nj] = (const short*)Wd + (size_t)(nj*16 + r)*K + kbase + kg*8;

  f32x4 acc[4];
  #pragma unroll
  for (int nj=0;nj<4;nj++) acc[nj] = (f32x4){0.f,0.f,0.f,0.f};

  for (int kk=0; kk<Kw; kk+=32){
    short8 a = *(const short8*)(Ap + kk);
    #pragma unroll
    for (int nj=0;nj<4;nj++){
      short8 wv = *(const short8*)(Wp[nj] + kk);
      acc[nj] = __builtin_amdgcn_mfma_f32_16x16x32_bf16(a, wv, acc[nj], 0,0,0);
    }
  }
  #pragma unroll
  for (int nj=0;nj<4;nj++)
    #pragma unroll
    for (int reg=0; reg<4; reg++){
      int rowt = kg*4 + reg;
      int col  = nj*16 + r;
      red[w*1024 + rowt*64 + col] = acc[nj][reg];
    }
  __syncthreads();
  int e0 = tid*4;
  f32x4 s = *(const f32x4*)&red[e0];
  #pragma unroll
  for (int ww=1; ww<4; ww++){
    f32x4 p = *(const f32x4*)&red[ww*1024 + e0];
    s.x += p.x; s.y += p.y; s.z += p.z; s.w += p.w;
  }
  int rowt = e0 >> 6, col = e0 & 63;
  *(f32x4*)&Cout[(size_t)(m0+rowt)*ldc + col] = s;
  if (col < 32){
    ushort4_t o = { f2bf_(s.x), f2bf_(s.y), f2bf_(s.z), f2bf_(s.w) };
    *(ushort4_t*)&dtb[(size_t)(m0+rowt)*32 + col] = o;
  }
}

// ---------------- big staged GEMM: 128(M)xBN(N) tile, BK=32, 4 waves ----------------
// BN=64 (proven R15/R20/R22 path): wave = 64x32 quadrant, 8 MFMA/step, 36KB, 4 blk/CU.
// BN=128 (R23-proven for in_proj; R24 extends to conv): wave = 64x64 quadrant,
//   16 MFMA/step, 48KB ring-3, 3 blk/CU max -- 2x MFMA-per-barrier at -25% occupancy.
// Ring-3, depth-2 prefetch, counted vmcnt(G), parity swizzle, XCD remap,
// nSeg K-split (seg s -> C0 + s*segBytes, bias on seg 0), uzMode, revA, per-dir bias.
template<bool OUTBF, int BN>
__global__ __launch_bounds__(256) void k_gemm_big(
    const __hip_bfloat16* __restrict__ A, int lda, int padExtra, int revA,
    const __hip_bfloat16* __restrict__ W, size_t wStride,
    void* __restrict__ C0, void* __restrict__ C1, size_t segBytes, int ldc, int coloff,
    int tiles_n, int baseBlocks, int totalBlocks, int Kc, int Kb,
    const float* __restrict__ bias0, const float* __restrict__ bias1, int act,
    const unsigned char* __restrict__ mask, int outRowSub, int dirColOff, int uzMode){
  constexpr int NJ = BN/32;                 // fragments per wave in N (2 or 4)
  constexpr int BUFE = 4096 + BN*32;        // elements per ring buffer
  __shared__ alignas(16) __hip_bfloat16 smem[3][BUFE];
  int b = blockIdx.x;
  int wg = (b & 7)*(totalBlocks >> 3) + (b >> 3);        // XCD-contiguous remap
  int seg = wg / baseBlocks;
  int bid = wg - seg*baseBlocks;
  int tn = bid % tiles_n;
  int tm = bid / tiles_n;
  int m0 = tm*128, n0 = tn*BN;
  int dir = m0 >> 12;
  int kOff = seg*Kc;
  const __hip_bfloat16* Wd = W + (size_t)dir*wStride;
  void* Cout = (void*)((char*)C0 + (size_t)seg*segBytes);
  const float* bsel = dir ? bias1 : bias0;
  const float* biasp = (bsel && seg==0) ? bsel : nullptr;

  int tid = threadIdx.x;
  int wid = tid >> 6, lane = tid & 63;
  int r = lane & 15, kg = lane >> 4;

  int sr = lane >> 2;
  int gs = (lane & 3) ^ ((sr >> 1) & 3);
  auto physrow = [&](int ar)->int{
    if (revA && ar >= 4096){
      int r2 = ar - 4096;
      return (r2 & ~1023) | (1023 - (r2 & 1023));
    }
    return ar + padExtra*(ar >> 10);
  };
  int arow0 = m0 + wid*16 + sr;
  int arow1 = arow0 + 64;
  size_t aoff0 = (size_t)physrow(arow0)*lda + kOff + gs*8;
  size_t aoff1 = (size_t)physrow(arow1)*lda + kOff + gs*8;
  size_t boffq[BN/64];
  #pragma unroll
  for (int q=0; q<BN/64; q++){
    int bcol = n0 + wid*16 + q*64 + sr;
    boffq[q] = (size_t)bcol*Kb + kOff + gs*8;
  }

  int wr = wid >> 1, wc = wid & 1;
  int xs = (kg ^ ((r >> 1) & 3))*8;
  int afrag[4], bfrag[NJ];
  #pragma unroll
  for (int mi=0; mi<4; mi++) afrag[mi] = (wr*64 + mi*16 + r)*32 + xs;
  #pragma unroll
  for (int nj=0; nj<NJ; nj++) bfrag[nj] = 4096 + (wc*(BN/2) + nj*16 + r)*32 + xs;

  f32x4 acc[4][NJ];
  #pragma unroll
  for (int mi=0;mi<4;mi++)
    #pragma unroll
    for (int nj=0;nj<NJ;nj++) acc[mi][nj] = (f32x4){0.f,0.f,0.f,0.f};

  const int nt = Kc >> 5;
  auto stage = [&](int kt, int bufi){
    __hip_bfloat16* sb = &smem[bufi][0];
    int k0 = kt*32;
    gload16((const short*)A + aoff0 + k0, sb + wid*512);
    gload16((const short*)A + aoff1 + k0, sb + (wid+4)*512);
    #pragma unroll
    for (int q=0; q<BN/64; q++)
      gload16((const short*)W + (size_t)(Wd - W) + boffq[q] + k0, sb + 4096 + (q*4 + wid)*512);
  };
  auto compute = [&](int bufi){
    const __hip_bfloat16* sb = &smem[bufi][0];
    short8 a[4], bb2[NJ];
    #pragma unroll
    for (int mi=0;mi<4;mi++) a[mi] = *(const short8*)&sb[afrag[mi]];
    #pragma unroll
    for (int nj=0;nj<NJ;nj++) bb2[nj] = *(const short8*)&sb[bfrag[nj]];
    #pragma unroll
    for (int mi=0;mi<4;mi++)
      #pragma unroll
      for (int nj=0;nj<NJ;nj++)
        acc[mi][nj] = __builtin_amdgcn_mfma_f32_16x16x32_bf16(a[mi], bb2[nj], acc[mi][nj], 0,0,0);
  };

  if (nt >= 3){
    stage(0, 0);
    stage(1, 1);
    int bi = 0;
    #pragma unroll 1
    for (int t=0; t<nt; t++){
      if (t+1 < nt){
        if constexpr (BN == 64) asm volatile("s_waitcnt vmcnt(3)" ::: "memory");
        else                    asm volatile("s_waitcnt vmcnt(4)" ::: "memory");
      } else {
        asm volatile("s_waitcnt vmcnt(0)" ::: "memory");
      }
      __builtin_amdgcn_s_barrier();
      __builtin_amdgcn_sched_barrier(0);
      if (t+2 < nt){
        int nb2 = bi + 2; if (nb2 >= 3) nb2 -= 3;
        stage(t+2, nb2);
      }
      compute(bi);
      bi = (bi+1 == 3) ? 0 : bi+1;
    }
  } else {
    for (int s=0; s<nt; s++) stage(s, s);
    asm volatile("s_waitcnt vmcnt(0)" ::: "memory");
    __builtin_amdgcn_s_barrier();
    __builtin_amdgcn_sched_barrier(0);
    for (int t=0; t<nt; t++) compute(t);
  }

  #pragma unroll
  for (int mi=0;mi<4;mi++){
    #pragma unroll
    for (int nj=0;nj<NJ;nj++){
      #pragma unroll
      for (int reg=0; reg<4; reg++){
        int row = m0 + wr*64 + mi*16 + kg*4 + reg;
        int col = n0 + wc*(BN/2) + nj*16 + r;
        float v = acc[mi][nj][reg];
        if (uzMode){
          if (col < 1024) ((__hip_bfloat16*)C0)[(size_t)row*1024 + col] = __float2bfloat16(v);
          else            ((__hip_bfloat16*)C1)[(size_t)row*1024 + (col-1024)] = __float2bfloat16(v);
          continue;
        }
        if (biasp) v += biasp[col];
        if (act == 1) v = softplus_(v);
        int row_out = row - dir*outRowSub;
        if (mask && mask[row_out]) v = 0.f;
        size_t o = (size_t)row_out*ldc + coloff + dir*dirColOff + col;
        if (OUTBF) ((__hip_bfloat16*)Cout)[o] = __float2bfloat16(v);
        else       ((float*)Cout)[o] = v;
      }
    }
  }
}

// ---------------- mamba pieces (batched: rows 0..8191, dir = row>>12) ----------------

// depthwise conv over bf16 u_pre -> bf16 ub only
__global__ void k_dwconv(const unsigned short* __restrict__ upre,
                         const float* __restrict__ cw0, const float* __restrict__ cw1,
                         const float* __restrict__ cb0, const float* __restrict__ cb1,
                         __hip_bfloat16* __restrict__ ub){
  int i = blockIdx.x*256 + threadIdx.x;     // over BL2*DI/4
  if (i >= BL2*DI/4) return;
  int d4 = i & (DI/4 - 1);
  int d = d4 << 2;
  int row = i >> 8;
  int dir = row >> 12;
  const float* cw = (dir ? cw1 : cw0) + d*4;
  const float* cb = (dir ? cb1 : cb0) + d;
  int l = row & 1023;
  int rb = row & ~1023;
  f32x4 cwv[4];
  #pragma unroll
  for (int j=0;j<4;j++) cwv[j] = *(const f32x4*)&cw[j*4];
  f32x4 acc = *(const f32x4*)cb;
  #pragma unroll
  for (int k=0;k<4;k++){
    int ll = l - 3 + k;
    if (ll >= 0){
      ushort4_t xv = *(const ushort4_t*)&upre[(size_t)(rb + ll)*DI + d];
      acc.x = __fmaf_rn(cwv[0][k], b2f_(xv.x), acc.x);
      acc.y = __fmaf_rn(cwv[1][k], b2f_(xv.y), acc.y);
      acc.z = __fmaf_rn(cwv[2][k], b2f_(xv.z), acc.z);
      acc.w = __fmaf_rn(cwv[3][k], b2f_(xv.w), acc.w);
    }
  }
  f32x4 s;
  s.x = acc.x * sigmoidf_(acc.x);
  s.y = acc.y * sigmoidf_(acc.y);
  s.z = acc.z * sigmoidf_(acc.z);
  s.w = acc.w * sigmoidf_(acc.w);
  ushort4_t o = { f2bf_(s.x), f2bf_(s.y), f2bf_(s.z), f2bf_(s.w) };
  *(ushort4_t*)((unsigned short*)ub + (size_t)i*4) = o;
}

// -------- chunked selective scan, thread-per-d, both dirs in one dispatch --------
// Af prescaled by log2(e); dA via __builtin_amdgcn_exp2f (single v_exp_f32).
// dv/uv(/zv) streams software-pipelined in groups of 8; dv,u,z all read as bf16.

__global__ __launch_bounds__(256) void k_scan_part(
    const float* __restrict__ Alog0, const float* __restrict__ Alog1,
    const unsigned short* __restrict__ dyb, const unsigned short* __restrict__ ub,
    const float* __restrict__ xdbc,
    float* __restrict__ Hp, float* __restrict__ Pp){
  __shared__ alignas(16) float Bsh[CLEN*16];
  int t = threadIdx.x;
  int dblk = blockIdx.x & 3;
  int c = (blockIdx.x >> 2) & (NCH-1);
  int b8 = blockIdx.x >> 7;
  const float* A_log = (b8 >> 2) ? Alog1 : Alog0;
  int d = dblk*256 + t;
  size_t blbase = (size_t)b8*LSEQ + (size_t)c*CLEN;
  if (t < CLEN*4){
    int l = t >> 2, q = t & 3;
    *(f32x4*)&Bsh[l*16 + q*4] = *(const f32x4*)&xdbc[(blbase+l)*64 + 32 + q*4];
  }
  float Af[16];
  #pragma unroll
  for (int n=0; n<16; n+=4){
    f32x4 a = *(const f32x4*)&A_log[(size_t)d*16 + n];
    Af[n]   = -__expf(a.x)*1.442695041f; Af[n+1] = -__expf(a.y)*1.442695041f;
    Af[n+2] = -__expf(a.z)*1.442695041f; Af[n+3] = -__expf(a.w)*1.442695041f;
  }
  float h[16];
  #pragma unroll
  for (int n=0;n<16;n++) h[n]=0.f;
  float Sdv = 0.f;
  const unsigned short* dyp = dyb + blbase*DI + d;
  const unsigned short* ubp = ub + blbase*DI + d;
  float dvb[2][8], uvb[2][8];
  #pragma unroll
  for (int j=0;j<8;j++){ dvb[0][j] = b2f_(dyp[(size_t)j*DI]); uvb[0][j] = b2f_(ubp[(size_t)j*DI]); }
  __syncthreads();
  #pragma unroll
  for (int g=0; g<4; g++){
    int cur = g & 1;
    if (g+1 < 4){
      int nxt = cur ^ 1;
      #pragma unroll
      for (int j=0;j<8;j++){
        size_t l = (size_t)(g+1)*8 + j;
        dvb[nxt][j] = b2f_(dyp[l*DI]); uvb[nxt][j] = b2f_(ubp[l*DI]);
      }
    }
    #pragma unroll
    for (int j=0;j<8;j++){
      int l = g*8 + j;
      float dv = dvb[cur][j], uv = uvb[cur][j];
      float duv = dv*uv;
      Sdv += dv;
      #pragma unroll
      for (int n=0;n<16;n++){
        float dA = fexp2_(dv*Af[n]);
        h[n] = __fmaf_rn(dA, h[n], duv*Bsh[l*16+n]);
      }
    }
  }
  size_t pb = (((size_t)(b8*NCH + c))*DI + d)*16;
  #pragma unroll
  for (int n=0;n<16;n+=4){
    *(f32x4*)&Hp[pb+n] = (f32x4){h[n],h[n+1],h[n+2],h[n+3]};
    *(f32x4*)&Pp[pb+n] = (f32x4){fexp2_(Af[n]*Sdv), fexp2_(Af[n+1]*Sdv),
                                 fexp2_(Af[n+2]*Sdv), fexp2_(Af[n+3]*Sdv)};
  }
}

// combine: h_in[c+1] = P[c]*h_in[c] + H[c]; writes h_in back into Pp (in place)
__global__ void k_scan_comb(float* __restrict__ Hp, float* __restrict__ Pp){
  int i = blockIdx.x*256 + threadIdx.x;   // (row8k)*16 + n
  if (i >= BL2*NST) return;
  int n = i & 15, row = i >> 4;
  int b8 = row >> 10, d = row & 1023;
  float hin = 0.f;
  #pragma unroll
  for (int c=0;c<NCH;c++){
    size_t idx = (((size_t)(b8*NCH + c))*DI + d)*16 + n;
    float P = Pp[idx], H = Hp[idx];
    Pp[idx] = hin;
    hin = __fmaf_rn(P, hin, H);
  }
}

// final pass: recompute chunk states from h_in, emit y fused with ygate -> yb (bf16)
__global__ __launch_bounds__(256) void k_scan_fin(
    const float* __restrict__ Alog0, const float* __restrict__ Alog1,
    const unsigned short* __restrict__ dyb, const unsigned short* __restrict__ ub,
    const float* __restrict__ xdbc,
    const float* __restrict__ Hin, const unsigned short* __restrict__ zb,
    const float* __restrict__ Dp0, const float* __restrict__ Dp1,
    __hip_bfloat16* __restrict__ yb){
  __shared__ alignas(16) float BCsh[CLEN*32];
  int t = threadIdx.x;
  int dblk = blockIdx.x & 3;
  int c = (blockIdx.x >> 2) & (NCH-1);
  int b8 = blockIdx.x >> 7;
  int dirb = b8 >> 2;
  const float* A_log = dirb ? Alog1 : Alog0;
  const float* Dp = dirb ? Dp1 : Dp0;
  int d = dblk*256 + t;
  size_t blbase = (size_t)b8*LSEQ + (size_t)c*CLEN;
  {
    int l = t >> 3, q = t & 7;
    *(f32x4*)&BCsh[l*32 + q*4] = *(const f32x4*)&xdbc[(blbase+l)*64 + 32 + q*4];
  }
  float Af[16];
  #pragma unroll
  for (int n=0; n<16; n+=4){
    f32x4 a = *(const f32x4*)&A_log[(size_t)d*16 + n];
    Af[n]   = -__expf(a.x)*1.442695041f; Af[n+1] = -__expf(a.y)*1.442695041f;
    Af[n+2] = -__expf(a.z)*1.442695041f; Af[n+3] = -__expf(a.w)*1.442695041f;
  }
  size_t pb = (((size_t)(b8*NCH + c))*DI + d)*16;
  float h[16];
  #pragma unroll
  for (int n=0;n<16;n+=4){
    f32x4 hv = *(const f32x4*)&Hin[pb+n];
    h[n]=hv.x; h[n+1]=hv.y; h[n+2]=hv.z; h[n+3]=hv.w;
  }
  float Dd = Dp[d];
  const unsigned short* dyp = dyb + blbase*DI + d;
  const unsigned short* ubp = ub + blbase*DI + d;
  const unsigned short* zp  = zb + blbase*DI + d;
  float dvb[2][8], uvb[2][8], zvb[2][8];
  #pragma unroll
  for (int j=0;j<8;j++){
    dvb[0][j] = b2f_(dyp[(size_t)j*DI]);
    uvb[0][j] = b2f_(ubp[(size_t)j*DI]);
    zvb[0][j] = b2f_(zp[(size_t)j*DI]);
  }
  __syncthreads();
  #pragma unroll
  for (int g=0; g<4; g++){
    int cur = g & 1;
    if (g+1 < 4){
      int nxt = cur ^ 1;
      #pragma unroll
      for (int j=0;j<8;j++){
        size_t l = (size_t)(g+1)*8 + j;
        dvb[nxt][j] = b2f_(dyp[l*DI]);
        uvb[nxt][j] = b2f_(ubp[l*DI]);
        zvb[nxt][j] = b2f_(zp[l*DI]);
      }
    }
    #pragma unroll
    for (int j=0;j<8;j++){
      int l = g*8 + j;
      float dv = dvb[cur][j], uv = uvb[cur][j], zv = zvb[cur][j];
      float duv = dv*uv;
      float y = 0.f;
      #pragma unroll
      for (int n=0;n<16;n++){
        float dA = fexp2_(dv*Af[n]);
        h[n] = __fmaf_rn(dA, h[n], duv*BCsh[l*32+n]);
        y = __fmaf_rn(h[n], BCsh[l*32+16+n], y);
      }
      float gg = zv * sigmoidf_(zv);
      float out = __fmaf_rn(uv, Dd, y) * gg;
      yb[(blbase+l)*DI + d] = __float2bfloat16(out);
    }
  }
}

// ---------------- host ----------------

extern "C" void kernel_launch(void* const* d_in, const int* in_sizes, int n_in,
                              void* d_out, int out_size, void* d_ws, size_t ws_size,
                              hipStream_t stream){
  (void)in_sizes; (void)n_in; (void)out_size; (void)ws_size;
  const int*   x     = (const int*)d_in[0];
  const unsigned char* m = (const unsigned char*)d_in[2];
  const float* emb   = (const float*)d_in[3];
  const float* convw = (const float*)d_in[4];
  const float* convb = (const float*)d_in[5];
  const float* lng   = (const float*)d_in[6];
  const float* lnb   = (const float*)d_in[7];
  const float* projw = (const float*)d_in[8];
  const float* projb = (const float*)d_in[9];

  char* ws = (char*)d_ws;
  size_t off = 0;
  auto alloc = [&](size_t bytes)->char*{
    char* p = ws + off; off += (bytes + 255) & ~((size_t)255); return p;
  };
  auto wt_conv = (__hip_bfloat16*)alloc((size_t)3*CCH*CCH*5*2);
  auto w_in2  = (__hip_bfloat16*)alloc((size_t)2*2*DI*CCH*2);
  auto w_x2   = (__hip_bfloat16*)alloc((size_t)2*64*DI*2);
  auto w_dt2  = (__hip_bfloat16*)alloc((size_t)2*DI*DTR*2);
  auto w_out2 = (__hip_bfloat16*)alloc((size_t)2*CCH*DI*2);
  auto w_proj = (__hip_bfloat16*)alloc((size_t)CCH*1024*2);
  auto xpad0  = (__hip_bfloat16*)alloc((size_t)BSZ*(LSEQ+4)*CCH*2);
  auto xpad1  = (__hip_bfloat16*)alloc((size_t)BSZ*(LSEQ+4)*CCH*2);
  auto scr    = (float*)alloc((size_t)8*NCH*DI*NST*4);   // 16.78 MB: 4x bf16 conv partials / scan Hp
  auto h_enc  = (__hip_bfloat16*)alloc((size_t)BL*CCH*2);
  auto upre   = (unsigned short*)alloc((size_t)BL2*DI*2);  // in_proj u-half, bf16
  auto zb     = (unsigned short*)alloc((size_t)BL2*DI*2);  // in_proj z-half, bf16
  auto ub2    = (__hip_bfloat16*)alloc((size_t)BL2*DI*2);  // conv'd u, bf16
  auto xdbc2  = (float*)alloc((size_t)BL2*64*4);
  auto dtb2   = (unsigned short*)alloc((size_t)BL2*DTR*2);
  auto dy2    = (unsigned short*)alloc((size_t)BL2*DI*2);  // delta bf16
  auto yb2    = (__hip_bfloat16*)alloc((size_t)BL2*DI*2);
  auto fob    = (__hip_bfloat16*)alloc((size_t)BL*DI*2);
  auto Pp     = (float*)alloc((size_t)8*NCH*DI*NST*4);

  float* Hp = scr;

  auto nb = [](size_t n){ return (unsigned)((n + 255)/256); };

  // --- weight prep ---
  k_prep_convw<<<dim3(nb((size_t)3*CCH*CCH*5)), dim3(256), 0, stream>>>(convw, wt_conv);
  {
    CastArgs ca;
    unsigned acc = 0;
    auto put = [&](int k, const void* s, void* d, unsigned n4){
      ca.e[k].s = (const float*)s; ca.e[k].d = (unsigned short*)d;
      ca.e[k].n4 = n4; ca.e[k].acc = acc; acc += n4;
    };
    for (int dir=0; dir<2; dir++){
      int base = 10 + 9*dir;
      put(dir*4+0, d_in[base+0], (unsigned short*)w_in2  + (size_t)dir*2*DI*CCH, (2*DI*CCH)/4);
      put(dir*4+1, d_in[base+3], (unsigned short*)w_x2   + (size_t)dir*64*DI,    (64*DI)/4);
      put(dir*4+2, d_in[base+4], (unsigned short*)w_dt2  + (size_t)dir*DI*DTR,   (DI*DTR)/4);
      put(dir*4+3, d_in[base+8], (unsigned short*)w_out2 + (size_t)dir*CCH*DI,   (CCH*DI)/4);
    }
    put(8, projw, w_proj, (CCH*1024)/4);
    ca.total4 = acc;
    k_cast_all<<<dim3(nb(acc)), dim3(256), 0, stream>>>(ca);
  }

  auto gemm_big = [&](const void* A, int lda, int padE, int revA, const void* W, size_t wStride,
                  void* C0, void* C1, size_t segBytes, int ldc, int coloff,
                  int M, int N, int Kc, int Kb, int nSeg,
                  const float* bias0, const float* bias1, int act,
                  const unsigned char* msk, int outRowSub, int dirColOff, bool outbf, int uzMode,
                  int bn){
    int tiles_n = N/bn;
    int baseBlocks = (M/128)*tiles_n;
    int blocks = baseBlocks * nSeg;
    if (bn == 128){
      if (outbf)
        k_gemm_big<true,128><<<dim3(blocks), dim3(256), 0, stream>>>((const __hip_bfloat16*)A, lda, padE, revA,
            (const __hip_bfloat16*)W, wStride, C0, C1, segBytes, ldc, coloff, tiles_n, baseBlocks, blocks,
            Kc, Kb, bias0, bias1, act, msk, outRowSub, dirColOff, uzMode);
      else
        k_gemm_big<false,128><<<dim3(blocks), dim3(256), 0, stream>>>((const __hip_bfloat16*)A, lda, padE, revA,
            (const __hip_bfloat16*)W, wStride, C0, C1, segBytes, ldc, coloff, tiles_n, baseBlocks, blocks,
            Kc, Kb, bias0, bias1, act, msk, outRowSub, dirColOff, uzMode);
    } else {
      if (outbf)
        k_gemm_big<true,64><<<dim3(blocks), dim3(256), 0, stream>>>((const __hip_bfloat16*)A, lda, padE, revA,
            (const __hip_bfloat16*)W, wStride, C0, C1, segBytes, ldc, coloff, tiles_n, baseBlocks, blocks,
            Kc, Kb, bias0, bias1, act, msk, outRowSub, dirColOff, uzMode);
      else
        k_gemm_big<false,64><<<dim3(blocks), dim3(256), 0, stream>>>((const __hip_bfloat16*)A, lda, padE, revA,
            (const __hip_bfloat16*)W, wStride, C0, C1, segBytes, ldc, coloff, tiles_n, baseBlocks, blocks,
            Kc, Kb, bias0, bias1, act, msk, outRowSub, dirColOff, uzMode);
    }
  };

  // --- encoder: embed(+pad-zero) + 3x (conv-as-GEMM BN=128 4-way K-split, bf16 partials -> LN(sum4)) ---
  k_embed<<<dim3(nb((size_t)BSZ*(LSEQ+4)*CCH + BSZ*4*CCH)), dim3(256), 0, stream>>>(x, emb, xpad0, xpad1);

  __hip_bfloat16* xp_in = xpad0;
  __hip_bfloat16* xp_out = xpad1;
  const size_t segB_conv = (size_t)BL*CCH*2;   // 4 bf16 partial slices inside scr (4 x 4 MB)
  unsigned short* cp = (unsigned short*)scr;
  for (int layer=0; layer<3; layer++){
    const __hip_bfloat16* wt = wt_conv + (size_t)layer*CCH*CCH*5;
    gemm_big(xp_in, CCH, 4, 0, wt, 0, cp, nullptr, segB_conv, CCH, 0, BL, CCH, 640, 2560, 4,
             convb + layer*CCH, convb + layer*CCH, 0, nullptr, 0, 0, true, 0, 128);
    bool last = (layer==2);
    k_ln<<<dim3(BL), dim3(256), 0, stream>>>(cp, cp + (size_t)BL*CCH, cp + (size_t)2*BL*CCH, cp + (size_t)3*BL*CCH,
        lng + layer*CCH, lnb + layer*CCH, m,
        last ? nullptr : xp_out, last ? h_enc : nullptr);
    __hip_bfloat16* t2 = xp_in; xp_in = xp_out; xp_out = t2;
  }

  // --- bidirectional mamba, both directions batched (rows 0..8191, dir = row>>12);
  //     dir-1 reads h_enc reversed via revA (no materialized h_rev) ---
  const float* Alog0 = (const float*)d_in[16];
  const float* Alog1 = (const float*)d_in[25];
  const float* Dp0   = (const float*)d_in[17];
  const float* Dp1   = (const float*)d_in[26];

  // in_proj: BN=128 (R23-proven: 1024 blocks, 48KB ring-3, 16 MFMA/wave/step)
  gemm_big(h_enc, CCH, 0, 1, w_in2, (size_t)2*DI*CCH, upre, zb, 0, 2*DI, 0,
           BL2, 2*DI, CCH, CCH, 1, nullptr, nullptr, 0, nullptr, 0, 0, false, 1, 128);
  k_dwconv<<<dim3(nb((size_t)BL2*DI/4)), dim3(256), 0, stream>>>(upre,
      (const float*)d_in[11], (const float*)d_in[20],
      (const float*)d_in[12], (const float*)d_in[21], ub2);
  k_gemm_ksplit<<<dim3(BL2/16), dim3(256), 0, stream>>>(ub2, DI, w_x2, (size_t)64*DI, xdbc2, 64, DI, dtb2);
  gemm_big(dtb2, DTR, 0, 0, w_dt2, (size_t)DI*DTR, dy2, nullptr, 0, DI, 0,
           BL2, DI, DTR, DTR, 1, (const float*)d_in[15], (const float*)d_in[24], 1,
           nullptr, 0, 0, true, 0, 64);
  k_scan_part<<<dim3(1024), dim3(256), 0, stream>>>(Alog0, Alog1, dy2, (const unsigned short*)ub2, xdbc2, Hp, Pp);
  k_scan_comb<<<dim3(nb((size_t)BL2*NST)), dim3(256), 0, stream>>>(Hp, Pp);
  k_scan_fin<<<dim3(1024), dim3(256), 0, stream>>>(Alog0, Alog1, dy2, (const unsigned short*)ub2, xdbc2, Pp, zb, Dp0, Dp1, yb2);
  gemm_big(yb2, DI, 0, 0, w_out2, (size_t)CCH*DI, fob, nullptr, 0, DI, 0,
           BL2, CCH, DI, DI, 1, nullptr, nullptr, 0, nullptr, BL, 512, true, 0, 64);

  // --- final projection + bias + mask -> d_out (f32) ---
  gemm_big(fob, DI, 0, 0, w_proj, 0, d_out, nullptr, 0, CCH, 0,
           BL, CCH, DI, DI, 1, projb, projb, 0, m, 0, 0, false, 0, 64);
}

// Round 25
// 300.821 us; speedup vs baseline: 1.0636x; 1.0636x over previous
//
#include <hip/hip_runtime.h>
#include <hip/hip_bf16.h>

typedef __attribute__((ext_vector_type(8))) short short8;
typedef __attribute__((ext_vector_type(4))) float f32x4;
typedef __attribute__((ext_vector_type(4))) unsigned short ushort4_t;

#define BSZ 4
#define LSEQ 1024
#define CCH 512
#define BL (BSZ*LSEQ)   // 4096 rows
#define BL2 (2*BL)      // both directions batched: 8192 rows
#define DI 1024         // d_inner
#define NST 16
#define DTR 32
#define NCH 32          // scan chunks
#define CLEN 32         // chunk length (NCH*CLEN == LSEQ)

__device__ __forceinline__ float sigmoidf_(float x){ return 1.f/(1.f+__expf(-x)); }
// fast softplus: v_exp + add + v_log -- the OCML log1pf path is ~30 VALU inst (R14 lesson)
__device__ __forceinline__ float softplus_(float x){ return x > 20.f ? x : __logf(1.f + __expf(x)); }
__device__ __forceinline__ float fexp2_(float x){ return __builtin_amdgcn_exp2f(x); }  // raw v_exp_f32
__device__ __forceinline__ unsigned short f2bf_(float f){
  __hip_bfloat16 h = __float2bfloat16(f); return *(unsigned short*)&h;
}
__device__ __forceinline__ float b2f_(unsigned short s){
  unsigned u = ((unsigned)s) << 16; float f; __builtin_memcpy(&f, &u, 4); return f;
}

typedef const __attribute__((address_space(1))) unsigned int* gas_t;
typedef __attribute__((address_space(3))) unsigned int* las_t;
__device__ __forceinline__ void gload16(const void* g, void* l){
  __builtin_amdgcn_global_load_lds((gas_t)g, (las_t)l, 16, 0, 0);
}

// ---------------- prep / elementwise kernels ----------------

// all 9 f32->bf16 weight casts in ONE launch (region table in kernarg)
struct CastEnt { const float* s; unsigned short* d; unsigned n4, acc; };
struct CastArgs { CastEnt e[9]; unsigned total4; };
__global__ void k_cast_all(CastArgs a){
  unsigned i = blockIdx.x*256 + threadIdx.x;
  if (i >= a.total4) return;
  #pragma unroll
  for (int k=0;k<9;k++){
    if (i < a.e[k].acc + a.e[k].n4){
      unsigned j = i - a.e[k].acc;
      float4 v = ((const float4*)a.e[k].s)[j];
      ushort4_t o = { f2bf_(v.x), f2bf_(v.y), f2bf_(v.z), f2bf_(v.w) };
      *(ushort4_t*)(a.e[k].d + (size_t)j*4) = o;
      return;
    }
  }
}

// conv_w [3][512][512][5] -> wt [3][512][2560], j = k*512 + ci  (matches contiguous patch)
__global__ void k_prep_convw(const float* __restrict__ cw, __hip_bfloat16* __restrict__ wt){
  int i = blockIdx.x*256 + threadIdx.x;
  const int total = 3*CCH*CCH*5;
  if (i >= total) return;
  int j = i % (CCH*5);
  int co = (i/(CCH*5)) % CCH;
  int layer = i/(CCH*5*CCH);
  int k = j >> 9, ci = j & 511;
  wt[i] = __float2bfloat16(cw[(((size_t)layer*CCH + co)*CCH + ci)*5 + k]);
}

// gather emb[x] into padded [B][L+4][C] bf16; tail range zeroes xpad1's 4 pad rows
__global__ void k_embed(const int* __restrict__ x, const float* __restrict__ emb,
                        __hip_bfloat16* __restrict__ xpad0, __hip_bfloat16* __restrict__ xpad1){
  int i = blockIdx.x*256 + threadIdx.x;
  const int total = BSZ*(LSEQ+4)*CCH;
  const int total2 = total + BSZ*4*CCH;
  if (i >= total2) return;
  if (i >= total){
    int j = i - total;
    int c = j & (CCH-1);
    int pr = (j >> 9) & 3;
    int b = j >> 11;
    int rr = (pr < 2) ? pr : (LSEQ+2) + (pr-2);
    xpad1[((size_t)b*(LSEQ+4) + rr)*CCH + c] = __float2bfloat16(0.f);
    return;
  }
  int c = i & (CCH-1);
  int r = (i >> 9) % (LSEQ+4);
  int b = i / ((LSEQ+4)*CCH);
  float v = 0.f;
  if (r >= 2 && r < LSEQ+2){
    int tok = x[b*LSEQ + (r-2)];
    v = emb[(size_t)tok*CCH + c];
  }
  xpad0[i] = __float2bfloat16(v);
}

// per-(b,l) channel LayerNorm over bf16 (in + in2) + scale/shift + LeakyReLU(0.2) + mask
__global__ __launch_bounds__(256) void k_ln(
    const unsigned short* __restrict__ in, const unsigned short* __restrict__ in2,
    const float* __restrict__ g, const float* __restrict__ bb,
    const unsigned char* __restrict__ mask,
    __hip_bfloat16* __restrict__ xpad_next,
    __hip_bfloat16* __restrict__ h_enc){
  int row = blockIdx.x;                 // b*1024 + l
  int b = row >> 10, l = row & 1023;
  size_t ro = (size_t)row*CCH;
  int t = threadIdx.x;
  float v0 = b2f_(in[ro+t]) + b2f_(in2[ro+t]);
  float v1 = b2f_(in[ro+t+256]) + b2f_(in2[ro+t+256]);
  float s = v0+v1, s2 = v0*v0 + v1*v1;
  #pragma unroll
  for (int off=32; off>0; off>>=1){ s += __shfl_down(s,off); s2 += __shfl_down(s2,off); }
  __shared__ float ls[8];
  if ((t&63)==0){ ls[t>>6] = s; ls[(t>>6)+4] = s2; }
  __syncthreads();
  float S  = ls[0]+ls[1]+ls[2]+ls[3];
  float S2 = ls[4]+ls[5]+ls[6]+ls[7];
  float mu = S*(1.f/CCH);
  float var = S2*(1.f/CCH) - mu*mu;
  float rs = rsqrtf(var + 1e-5f);
  bool mk = mask[row] != 0;
  #pragma unroll
  for (int e=0; e<2; e++){
    int c = t + e*256;
    float v = e ? v1 : v0;
    float h = (v-mu)*rs*g[c] + bb[c];
    h = h > 0.f ? h : 0.2f*h;
    if (mk) h = 0.f;
    __hip_bfloat16 hb = __float2bfloat16(h);
    if (xpad_next) xpad_next[((size_t)b*(LSEQ+4) + (l+2))*CCH + c] = hb;
    if (h_enc) h_enc[(size_t)row*CCH + c] = hb;
  }
}

// ---------------- K-split GEMM for skinny N=64 (x_proj), batched dirs ----------------
// 16 rows per block; 4 waves each own a K/4 slice; LDS reduce.
__global__ __launch_bounds__(256) void k_gemm_ksplit(
    const __hip_bfloat16* __restrict__ A, int lda,
    const __hip_bfloat16* __restrict__ W, size_t wStride,
    float* __restrict__ Cout, int ldc, int K, unsigned short* __restrict__ dtb){
  __shared__ float red[4*1024];   // 16 KB
  int m0 = blockIdx.x << 4;
  const __hip_bfloat16* Wd = W + (size_t)(m0 >> 12)*wStride;
  int tid = threadIdx.x;
  int w = tid >> 6, lane = tid & 63;
  int r = lane & 15, kg = lane >> 4;
  int Kw = K >> 2;
  int kbase = w*Kw;

  const short* Ap = (const short*)A + (size_t)(m0 + r)*lda + kbase + kg*8;
  const short* Wp[4];
  #pragma unroll
  for (int nj=0; nj<4; nj++)
    Wp[nj] = (const short*)Wd + (size_t)(nj*16 + r)*K + kbase + kg*8;

  f32x4 acc[4];
  #pragma unroll
  for (int nj=0;nj<4;nj++) acc[nj] = (f32x4){0.f,0.f,0.f,0.f};

  for (int kk=0; kk<Kw; kk+=32){
    short8 a = *(const short8*)(Ap + kk);
    #pragma unroll
    for (int nj=0;nj<4;nj++){
      short8 wv = *(const short8*)(Wp[nj] + kk);
      acc[nj] = __builtin_amdgcn_mfma_f32_16x16x32_bf16(a, wv, acc[nj], 0,0,0);
    }
  }
  #pragma unroll
  for (int nj=0;nj<4;nj++)
    #pragma unroll
    for (int reg=0; reg<4; reg++){
      int rowt = kg*4 + reg;
      int col  = nj*16 + r;
      red[w*1024 + rowt*64 + col] = acc[nj][reg];
    }
  __syncthreads();
  int e0 = tid*4;
  f32x4 s = *(const f32x4*)&red[e0];
  #pragma unroll
  for (int ww=1; ww<4; ww++){
    f32x4 p = *(const f32x4*)&red[ww*1024 + e0];
    s.x += p.x; s.y += p.y; s.z += p.z; s.w += p.w;
  }
  int rowt = e0 >> 6, col = e0 & 63;
  *(f32x4*)&Cout[(size_t)(m0+rowt)*ldc + col] = s;
  if (col < 32){
    ushort4_t o = { f2bf_(s.x), f2bf_(s.y), f2bf_(s.z), f2bf_(s.w) };
    *(ushort4_t*)&dtb[(size_t)(m0+rowt)*32 + col] = o;
  }
}

// ---------------- big staged GEMM: 128(M)xBN(N) tile, BK=32, 4 waves ----------------
// BN=64 (proven R15/R20/R22 path): wave = 64x32 quadrant, 8 MFMA/step, 36KB, 4 blk/CU.
// BN=128 (R23-proven, in_proj only): wave = 64x64 quadrant, 16 MFMA/step, 48KB, 3 blk/CU
//   -- 2x MFMA-per-barrier at only -25% occupancy; pays only at in_proj's 1024-block grid
//   (R24: transferring to conv regressed -- grid/partial-traffic conditions not met).
// Ring-3, depth-2 prefetch, counted vmcnt(G), parity swizzle, XCD remap,
// nSeg K-split (seg s -> C0 + s*segBytes, bias on seg 0), uzMode, revA, per-dir bias.
template<bool OUTBF, int BN>
__global__ __launch_bounds__(256) void k_gemm_big(
    const __hip_bfloat16* __restrict__ A, int lda, int padExtra, int revA,
    const __hip_bfloat16* __restrict__ W, size_t wStride,
    void* __restrict__ C0, void* __restrict__ C1, size_t segBytes, int ldc, int coloff,
    int tiles_n, int baseBlocks, int totalBlocks, int Kc, int Kb,
    const float* __restrict__ bias0, const float* __restrict__ bias1, int act,
    const unsigned char* __restrict__ mask, int outRowSub, int dirColOff, int uzMode){
  constexpr int NJ = BN/32;                 // fragments per wave in N (2 or 4)
  constexpr int BUFE = 4096 + BN*32;        // elements per ring buffer
  __shared__ alignas(16) __hip_bfloat16 smem[3][BUFE];
  int b = blockIdx.x;
  int wg = (b & 7)*(totalBlocks >> 3) + (b >> 3);        // XCD-contiguous remap
  int seg = wg / baseBlocks;
  int bid = wg - seg*baseBlocks;
  int tn = bid % tiles_n;
  int tm = bid / tiles_n;
  int m0 = tm*128, n0 = tn*BN;
  int dir = m0 >> 12;
  int kOff = seg*Kc;
  const __hip_bfloat16* Wd = W + (size_t)dir*wStride;
  void* Cout = (void*)((char*)C0 + (size_t)seg*segBytes);
  const float* bsel = dir ? bias1 : bias0;
  const float* biasp = (bsel && seg==0) ? bsel : nullptr;

  int tid = threadIdx.x;
  int wid = tid >> 6, lane = tid & 63;
  int r = lane & 15, kg = lane >> 4;

  int sr = lane >> 2;
  int gs = (lane & 3) ^ ((sr >> 1) & 3);
  auto physrow = [&](int ar)->int{
    if (revA && ar >= 4096){
      int r2 = ar - 4096;
      return (r2 & ~1023) | (1023 - (r2 & 1023));
    }
    return ar + padExtra*(ar >> 10);
  };
  int arow0 = m0 + wid*16 + sr;
  int arow1 = arow0 + 64;
  size_t aoff0 = (size_t)physrow(arow0)*lda + kOff + gs*8;
  size_t aoff1 = (size_t)physrow(arow1)*lda + kOff + gs*8;
  size_t boffq[BN/64];
  #pragma unroll
  for (int q=0; q<BN/64; q++){
    int bcol = n0 + wid*16 + q*64 + sr;
    boffq[q] = (size_t)bcol*Kb + kOff + gs*8;
  }

  int wr = wid >> 1, wc = wid & 1;
  int xs = (kg ^ ((r >> 1) & 3))*8;
  int afrag[4], bfrag[NJ];
  #pragma unroll
  for (int mi=0; mi<4; mi++) afrag[mi] = (wr*64 + mi*16 + r)*32 + xs;
  #pragma unroll
  for (int nj=0; nj<NJ; nj++) bfrag[nj] = 4096 + (wc*(BN/2) + nj*16 + r)*32 + xs;

  f32x4 acc[4][NJ];
  #pragma unroll
  for (int mi=0;mi<4;mi++)
    #pragma unroll
    for (int nj=0;nj<NJ;nj++) acc[mi][nj] = (f32x4){0.f,0.f,0.f,0.f};

  const int nt = Kc >> 5;
  auto stage = [&](int kt, int bufi){
    __hip_bfloat16* sb = &smem[bufi][0];
    int k0 = kt*32;
    gload16((const short*)A + aoff0 + k0, sb + wid*512);
    gload16((const short*)A + aoff1 + k0, sb + (wid+4)*512);
    #pragma unroll
    for (int q=0; q<BN/64; q++)
      gload16((const short*)W + (size_t)(Wd - W) + boffq[q] + k0, sb + 4096 + (q*4 + wid)*512);
  };
  auto compute = [&](int bufi){
    const __hip_bfloat16* sb = &smem[bufi][0];
    short8 a[4], bb2[NJ];
    #pragma unroll
    for (int mi=0;mi<4;mi++) a[mi] = *(const short8*)&sb[afrag[mi]];
    #pragma unroll
    for (int nj=0;nj<NJ;nj++) bb2[nj] = *(const short8*)&sb[bfrag[nj]];
    #pragma unroll
    for (int mi=0;mi<4;mi++)
      #pragma unroll
      for (int nj=0;nj<NJ;nj++)
        acc[mi][nj] = __builtin_amdgcn_mfma_f32_16x16x32_bf16(a[mi], bb2[nj], acc[mi][nj], 0,0,0);
  };

  if (nt >= 3){
    stage(0, 0);
    stage(1, 1);
    int bi = 0;
    #pragma unroll 1
    for (int t=0; t<nt; t++){
      if (t+1 < nt){
        if constexpr (BN == 64) asm volatile("s_waitcnt vmcnt(3)" ::: "memory");
        else                    asm volatile("s_waitcnt vmcnt(4)" ::: "memory");
      } else {
        asm volatile("s_waitcnt vmcnt(0)" ::: "memory");
      }
      __builtin_amdgcn_s_barrier();
      __builtin_amdgcn_sched_barrier(0);
      if (t+2 < nt){
        int nb2 = bi + 2; if (nb2 >= 3) nb2 -= 3;
        stage(t+2, nb2);
      }
      compute(bi);
      bi = (bi+1 == 3) ? 0 : bi+1;
    }
  } else {
    for (int s=0; s<nt; s++) stage(s, s);
    asm volatile("s_waitcnt vmcnt(0)" ::: "memory");
    __builtin_amdgcn_s_barrier();
    __builtin_amdgcn_sched_barrier(0);
    for (int t=0; t<nt; t++) compute(t);
  }

  #pragma unroll
  for (int mi=0;mi<4;mi++){
    #pragma unroll
    for (int nj=0;nj<NJ;nj++){
      #pragma unroll
      for (int reg=0; reg<4; reg++){
        int row = m0 + wr*64 + mi*16 + kg*4 + reg;
        int col = n0 + wc*(BN/2) + nj*16 + r;
        float v = acc[mi][nj][reg];
        if (uzMode){
          if (col < 1024) ((__hip_bfloat16*)C0)[(size_t)row*1024 + col] = __float2bfloat16(v);
          else            ((__hip_bfloat16*)C1)[(size_t)row*1024 + (col-1024)] = __float2bfloat16(v);
          continue;
        }
        if (biasp) v += biasp[col];
        if (act == 1) v = softplus_(v);
        int row_out = row - dir*outRowSub;
        if (mask && mask[row_out]) v = 0.f;
        size_t o = (size_t)row_out*ldc + coloff + dir*dirColOff + col;
        if (OUTBF) ((__hip_bfloat16*)Cout)[o] = __float2bfloat16(v);
        else       ((float*)Cout)[o] = v;
      }
    }
  }
}

// ---------------- mamba pieces (batched: rows 0..8191, dir = row>>12) ----------------

// depthwise conv over bf16 u_pre -> bf16 ub only
__global__ void k_dwconv(const unsigned short* __restrict__ upre,
                         const float* __restrict__ cw0, const float* __restrict__ cw1,
                         const float* __restrict__ cb0, const float* __restrict__ cb1,
                         __hip_bfloat16* __restrict__ ub){
  int i = blockIdx.x*256 + threadIdx.x;     // over BL2*DI/4
  if (i >= BL2*DI/4) return;
  int d4 = i & (DI/4 - 1);
  int d = d4 << 2;
  int row = i >> 8;
  int dir = row >> 12;
  const float* cw = (dir ? cw1 : cw0) + d*4;
  const float* cb = (dir ? cb1 : cb0) + d;
  int l = row & 1023;
  int rb = row & ~1023;
  f32x4 cwv[4];
  #pragma unroll
  for (int j=0;j<4;j++) cwv[j] = *(const f32x4*)&cw[j*4];
  f32x4 acc = *(const f32x4*)cb;
  #pragma unroll
  for (int k=0;k<4;k++){
    int ll = l - 3 + k;
    if (ll >= 0){
      ushort4_t xv = *(const ushort4_t*)&upre[(size_t)(rb + ll)*DI + d];
      acc.x = __fmaf_rn(cwv[0][k], b2f_(xv.x), acc.x);
      acc.y = __fmaf_rn(cwv[1][k], b2f_(xv.y), acc.y);
      acc.z = __fmaf_rn(cwv[2][k], b2f_(xv.z), acc.z);
      acc.w = __fmaf_rn(cwv[3][k], b2f_(xv.w), acc.w);
    }
  }
  f32x4 s;
  s.x = acc.x * sigmoidf_(acc.x);
  s.y = acc.y * sigmoidf_(acc.y);
  s.z = acc.z * sigmoidf_(acc.z);
  s.w = acc.w * sigmoidf_(acc.w);
  ushort4_t o = { f2bf_(s.x), f2bf_(s.y), f2bf_(s.z), f2bf_(s.w) };
  *(ushort4_t*)((unsigned short*)ub + (size_t)i*4) = o;
}

// -------- chunked selective scan, thread-per-d, both dirs in one dispatch --------
// Af prescaled by log2(e); dA via __builtin_amdgcn_exp2f (single v_exp_f32).
// dv/uv(/zv) streams software-pipelined in groups of 8; dv,u,z all read as bf16.

__global__ __launch_bounds__(256) void k_scan_part(
    const float* __restrict__ Alog0, const float* __restrict__ Alog1,
    const unsigned short* __restrict__ dyb, const unsigned short* __restrict__ ub,
    const float* __restrict__ xdbc,
    float* __restrict__ Hp, float* __restrict__ Pp){
  __shared__ alignas(16) float Bsh[CLEN*16];
  int t = threadIdx.x;
  int dblk = blockIdx.x & 3;
  int c = (blockIdx.x >> 2) & (NCH-1);
  int b8 = blockIdx.x >> 7;
  const float* A_log = (b8 >> 2) ? Alog1 : Alog0;
  int d = dblk*256 + t;
  size_t blbase = (size_t)b8*LSEQ + (size_t)c*CLEN;
  if (t < CLEN*4){
    int l = t >> 2, q = t & 3;
    *(f32x4*)&Bsh[l*16 + q*4] = *(const f32x4*)&xdbc[(blbase+l)*64 + 32 + q*4];
  }
  float Af[16];
  #pragma unroll
  for (int n=0; n<16; n+=4){
    f32x4 a = *(const f32x4*)&A_log[(size_t)d*16 + n];
    Af[n]   = -__expf(a.x)*1.442695041f; Af[n+1] = -__expf(a.y)*1.442695041f;
    Af[n+2] = -__expf(a.z)*1.442695041f; Af[n+3] = -__expf(a.w)*1.442695041f;
  }
  float h[16];
  #pragma unroll
  for (int n=0;n<16;n++) h[n]=0.f;
  float Sdv = 0.f;
  const unsigned short* dyp = dyb + blbase*DI + d;
  const unsigned short* ubp = ub + blbase*DI + d;
  float dvb[2][8], uvb[2][8];
  #pragma unroll
  for (int j=0;j<8;j++){ dvb[0][j] = b2f_(dyp[(size_t)j*DI]); uvb[0][j] = b2f_(ubp[(size_t)j*DI]); }
  __syncthreads();
  #pragma unroll
  for (int g=0; g<4; g++){
    int cur = g & 1;
    if (g+1 < 4){
      int nxt = cur ^ 1;
      #pragma unroll
      for (int j=0;j<8;j++){
        size_t l = (size_t)(g+1)*8 + j;
        dvb[nxt][j] = b2f_(dyp[l*DI]); uvb[nxt][j] = b2f_(ubp[l*DI]);
      }
    }
    #pragma unroll
    for (int j=0;j<8;j++){
      int l = g*8 + j;
      float dv = dvb[cur][j], uv = uvb[cur][j];
      float duv = dv*uv;
      Sdv += dv;
      #pragma unroll
      for (int n=0;n<16;n++){
        float dA = fexp2_(dv*Af[n]);
        h[n] = __fmaf_rn(dA, h[n], duv*Bsh[l*16+n]);
      }
    }
  }
  size_t pb = (((size_t)(b8*NCH + c))*DI + d)*16;
  #pragma unroll
  for (int n=0;n<16;n+=4){
    *(f32x4*)&Hp[pb+n] = (f32x4){h[n],h[n+1],h[n+2],h[n+3]};
    *(f32x4*)&Pp[pb+n] = (f32x4){fexp2_(Af[n]*Sdv), fexp2_(Af[n+1]*Sdv),
                                 fexp2_(Af[n+2]*Sdv), fexp2_(Af[n+3]*Sdv)};
  }
}

// combine: h_in[c+1] = P[c]*h_in[c] + H[c]; writes h_in back into Pp (in place)
__global__ void k_scan_comb(float* __restrict__ Hp, float* __restrict__ Pp){
  int i = blockIdx.x*256 + threadIdx.x;   // (row8k)*16 + n
  if (i >= BL2*NST) return;
  int n = i & 15, row = i >> 4;
  int b8 = row >> 10, d = row & 1023;
  float hin = 0.f;
  #pragma unroll
  for (int c=0;c<NCH;c++){
    size_t idx = (((size_t)(b8*NCH + c))*DI + d)*16 + n;
    float P = Pp[idx], H = Hp[idx];
    Pp[idx] = hin;
    hin = __fmaf_rn(P, hin, H);
  }
}

// final pass: recompute chunk states from h_in, emit y fused with ygate -> yb (bf16)
__global__ __launch_bounds__(256) void k_scan_fin(
    const float* __restrict__ Alog0, const float* __restrict__ Alog1,
    const unsigned short* __restrict__ dyb, const unsigned short* __restrict__ ub,
    const float* __restrict__ xdbc,
    const float* __restrict__ Hin, const unsigned short* __restrict__ zb,
    const float* __restrict__ Dp0, const float* __restrict__ Dp1,
    __hip_bfloat16* __restrict__ yb){
  __shared__ alignas(16) float BCsh[CLEN*32];
  int t = threadIdx.x;
  int dblk = blockIdx.x & 3;
  int c = (blockIdx.x >> 2) & (NCH-1);
  int b8 = blockIdx.x >> 7;
  int dirb = b8 >> 2;
  const float* A_log = dirb ? Alog1 : Alog0;
  const float* Dp = dirb ? Dp1 : Dp0;
  int d = dblk*256 + t;
  size_t blbase = (size_t)b8*LSEQ + (size_t)c*CLEN;
  {
    int l = t >> 3, q = t & 7;
    *(f32x4*)&BCsh[l*32 + q*4] = *(const f32x4*)&xdbc[(blbase+l)*64 + 32 + q*4];
  }
  float Af[16];
  #pragma unroll
  for (int n=0; n<16; n+=4){
    f32x4 a = *(const f32x4*)&A_log[(size_t)d*16 + n];
    Af[n]   = -__expf(a.x)*1.442695041f; Af[n+1] = -__expf(a.y)*1.442695041f;
    Af[n+2] = -__expf(a.z)*1.442695041f; Af[n+3] = -__expf(a.w)*1.442695041f;
  }
  size_t pb = (((size_t)(b8*NCH + c))*DI + d)*16;
  float h[16];
  #pragma unroll
  for (int n=0;n<16;n+=4){
    f32x4 hv = *(const f32x4*)&Hin[pb+n];
    h[n]=hv.x; h[n+1]=hv.y; h[n+2]=hv.z; h[n+3]=hv.w;
  }
  float Dd = Dp[d];
  const unsigned short* dyp = dyb + blbase*DI + d;
  const unsigned short* ubp = ub + blbase*DI + d;
  const unsigned short* zp  = zb + blbase*DI + d;
  float dvb[2][8], uvb[2][8], zvb[2][8];
  #pragma unroll
  for (int j=0;j<8;j++){
    dvb[0][j] = b2f_(dyp[(size_t)j*DI]);
    uvb[0][j] = b2f_(ubp[(size_t)j*DI]);
    zvb[0][j] = b2f_(zp[(size_t)j*DI]);
  }
  __syncthreads();
  #pragma unroll
  for (int g=0; g<4; g++){
    int cur = g & 1;
    if (g+1 < 4){
      int nxt = cur ^ 1;
      #pragma unroll
      for (int j=0;j<8;j++){
        size_t l = (size_t)(g+1)*8 + j;
        dvb[nxt][j] = b2f_(dyp[l*DI]);
        uvb[nxt][j] = b2f_(ubp[l*DI]);
        zvb[nxt][j] = b2f_(zp[l*DI]);
      }
    }
    #pragma unroll
    for (int j=0;j<8;j++){
      int l = g*8 + j;
      float dv = dvb[cur][j], uv = uvb[cur][j], zv = zvb[cur][j];
      float duv = dv*uv;
      float y = 0.f;
      #pragma unroll
      for (int n=0;n<16;n++){
        float dA = fexp2_(dv*Af[n]);
        h[n] = __fmaf_rn(dA, h[n], duv*BCsh[l*32+n]);
        y = __fmaf_rn(h[n], BCsh[l*32+16+n], y);
      }
      float gg = zv * sigmoidf_(zv);
      float out = __fmaf_rn(uv, Dd, y) * gg;
      yb[(blbase+l)*DI + d] = __float2bfloat16(out);
    }
  }
}

// ---------------- host ----------------

extern "C" void kernel_launch(void* const* d_in, const int* in_sizes, int n_in,
                              void* d_out, int out_size, void* d_ws, size_t ws_size,
                              hipStream_t stream){
  (void)in_sizes; (void)n_in; (void)out_size; (void)ws_size;
  const int*   x     = (const int*)d_in[0];
  const unsigned char* m = (const unsigned char*)d_in[2];
  const float* emb   = (const float*)d_in[3];
  const float* convw = (const float*)d_in[4];
  const float* convb = (const float*)d_in[5];
  const float* lng   = (const float*)d_in[6];
  const float* lnb   = (const float*)d_in[7];
  const float* projw = (const float*)d_in[8];
  const float* projb = (const float*)d_in[9];

  char* ws = (char*)d_ws;
  size_t off = 0;
  auto alloc = [&](size_t bytes)->char*{
    char* p = ws + off; off += (bytes + 255) & ~((size_t)255); return p;
  };
  auto wt_conv = (__hip_bfloat16*)alloc((size_t)3*CCH*CCH*5*2);
  auto w_in2  = (__hip_bfloat16*)alloc((size_t)2*2*DI*CCH*2);
  auto w_x2   = (__hip_bfloat16*)alloc((size_t)2*64*DI*2);
  auto w_dt2  = (__hip_bfloat16*)alloc((size_t)2*DI*DTR*2);
  auto w_out2 = (__hip_bfloat16*)alloc((size_t)2*CCH*DI*2);
  auto w_proj = (__hip_bfloat16*)alloc((size_t)CCH*1024*2);
  auto xpad0  = (__hip_bfloat16*)alloc((size_t)BSZ*(LSEQ+4)*CCH*2);
  auto xpad1  = (__hip_bfloat16*)alloc((size_t)BSZ*(LSEQ+4)*CCH*2);
  auto scr    = (float*)alloc((size_t)8*NCH*DI*NST*4);   // 16.78 MB: conv partial0 (bf16) / scan Hp
  auto h_enc  = (__hip_bfloat16*)alloc((size_t)BL*CCH*2);
  auto upre   = (unsigned short*)alloc((size_t)BL2*DI*2);  // in_proj u-half, bf16
  auto zb     = (unsigned short*)alloc((size_t)BL2*DI*2);  // in_proj z-half, bf16
  auto ub2    = (__hip_bfloat16*)alloc((size_t)BL2*DI*2);  // conv'd u, bf16
  auto xdbc2  = (float*)alloc((size_t)BL2*64*4);
  auto dtb2   = (unsigned short*)alloc((size_t)BL2*DTR*2);
  auto dy2    = (unsigned short*)alloc((size_t)BL2*DI*2);  // delta bf16
  auto convp1 = (unsigned short*)alloc((size_t)BL*CCH*2);  // conv partial1 (bf16, encoder only)
  auto yb2    = (__hip_bfloat16*)alloc((size_t)BL2*DI*2);
  auto fob    = (__hip_bfloat16*)alloc((size_t)BL*DI*2);
  auto Pp     = (float*)alloc((size_t)8*NCH*DI*NST*4);

  float* Hp = scr;

  auto nb = [](size_t n){ return (unsigned)((n + 255)/256); };

  // --- weight prep ---
  k_prep_convw<<<dim3(nb((size_t)3*CCH*CCH*5)), dim3(256), 0, stream>>>(convw, wt_conv);
  {
    CastArgs ca;
    unsigned acc = 0;
    auto put = [&](int k, const void* s, void* d, unsigned n4){
      ca.e[k].s = (const float*)s; ca.e[k].d = (unsigned short*)d;
      ca.e[k].n4 = n4; ca.e[k].acc = acc; acc += n4;
    };
    for (int dir=0; dir<2; dir++){
      int base = 10 + 9*dir;
      put(dir*4+0, d_in[base+0], (unsigned short*)w_in2  + (size_t)dir*2*DI*CCH, (2*DI*CCH)/4);
      put(dir*4+1, d_in[base+3], (unsigned short*)w_x2   + (size_t)dir*64*DI,    (64*DI)/4);
      put(dir*4+2, d_in[base+4], (unsigned short*)w_dt2  + (size_t)dir*DI*DTR,   (DI*DTR)/4);
      put(dir*4+3, d_in[base+8], (unsigned short*)w_out2 + (size_t)dir*CCH*DI,   (CCH*DI)/4);
    }
    put(8, projw, w_proj, (CCH*1024)/4);
    ca.total4 = acc;
    k_cast_all<<<dim3(nb(acc)), dim3(256), 0, stream>>>(ca);
  }

  auto gemm_big = [&](const void* A, int lda, int padE, int revA, const void* W, size_t wStride,
                  void* C0, void* C1, size_t segBytes, int ldc, int coloff,
                  int M, int N, int Kc, int Kb, int nSeg,
                  const float* bias0, const float* bias1, int act,
                  const unsigned char* msk, int outRowSub, int dirColOff, bool outbf, int uzMode,
                  int bn){
    int tiles_n = N/bn;
    int baseBlocks = (M/128)*tiles_n;
    int blocks = baseBlocks * nSeg;
    if (bn == 128){
      if (outbf)
        k_gemm_big<true,128><<<dim3(blocks), dim3(256), 0, stream>>>((const __hip_bfloat16*)A, lda, padE, revA,
            (const __hip_bfloat16*)W, wStride, C0, C1, segBytes, ldc, coloff, tiles_n, baseBlocks, blocks,
            Kc, Kb, bias0, bias1, act, msk, outRowSub, dirColOff, uzMode);
      else
        k_gemm_big<false,128><<<dim3(blocks), dim3(256), 0, stream>>>((const __hip_bfloat16*)A, lda, padE, revA,
            (const __hip_bfloat16*)W, wStride, C0, C1, segBytes, ldc, coloff, tiles_n, baseBlocks, blocks,
            Kc, Kb, bias0, bias1, act, msk, outRowSub, dirColOff, uzMode);
    } else {
      if (outbf)
        k_gemm_big<true,64><<<dim3(blocks), dim3(256), 0, stream>>>((const __hip_bfloat16*)A, lda, padE, revA,
            (const __hip_bfloat16*)W, wStride, C0, C1, segBytes, ldc, coloff, tiles_n, baseBlocks, blocks,
            Kc, Kb, bias0, bias1, act, msk, outRowSub, dirColOff, uzMode);
      else
        k_gemm_big<false,64><<<dim3(blocks), dim3(256), 0, stream>>>((const __hip_bfloat16*)A, lda, padE, revA,
            (const __hip_bfloat16*)W, wStride, C0, C1, segBytes, ldc, coloff, tiles_n, baseBlocks, blocks,
            Kc, Kb, bias0, bias1, act, msk, outRowSub, dirColOff, uzMode);
    }
  };

  // --- encoder: embed(+pad-zero) + 3x (conv-as-GEMM BN=64 2-way K-split, bf16 partials -> LN) ---
  k_embed<<<dim3(nb((size_t)BSZ*(LSEQ+4)*CCH + BSZ*4*CCH)), dim3(256), 0, stream>>>(x, emb, xpad0, xpad1);

  __hip_bfloat16* xp_in = xpad0;
  __hip_bfloat16* xp_out = xpad1;
  const size_t segB_conv = (size_t)((char*)convp1 - (char*)scr);   // seg1 -> convp1
  for (int layer=0; layer<3; layer++){
    const __hip_bfloat16* wt = wt_conv + (size_t)layer*CCH*CCH*5;
    gemm_big(xp_in, CCH, 4, 0, wt, 0, scr, nullptr, segB_conv, CCH, 0, BL, CCH, 1280, 2560, 2,
             convb + layer*CCH, convb + layer*CCH, 0, nullptr, 0, 0, true, 0, 64);
    bool last = (layer==2);
    k_ln<<<dim3(BL), dim3(256), 0, stream>>>((const unsigned short*)scr, convp1,
        lng + layer*CCH, lnb + layer*CCH, m,
        last ? nullptr : xp_out, last ? h_enc : nullptr);
    __hip_bfloat16* t2 = xp_in; xp_in = xp_out; xp_out = t2;
  }

  // --- bidirectional mamba, both directions batched (rows 0..8191, dir = row>>12);
  //     dir-1 reads h_enc reversed via revA (no materialized h_rev) ---
  const float* Alog0 = (const float*)d_in[16];
  const float* Alog1 = (const float*)d_in[25];
  const float* Dp0   = (const float*)d_in[17];
  const float* Dp1   = (const float*)d_in[26];

  // in_proj: BN=128 (R23-proven: 1024 blocks, 48KB ring-3, 16 MFMA/wave/step)
  gemm_big(h_enc, CCH, 0, 1, w_in2, (size_t)2*DI*CCH, upre, zb, 0, 2*DI, 0,
           BL2, 2*DI, CCH, CCH, 1, nullptr, nullptr, 0, nullptr, 0, 0, false, 1, 128);
  k_dwconv<<<dim3(nb((size_t)BL2*DI/4)), dim3(256), 0, stream>>>(upre,
      (const float*)d_in[11], (const float*)d_in[20],
      (const float*)d_in[12], (const float*)d_in[21], ub2);
  k_gemm_ksplit<<<dim3(BL2/16), dim3(256), 0, stream>>>(ub2, DI, w_x2, (size_t)64*DI, xdbc2, 64, DI, dtb2);
  gemm_big(dtb2, DTR, 0, 0, w_dt2, (size_t)DI*DTR, dy2, nullptr, 0, DI, 0,
           BL2, DI, DTR, DTR, 1, (const float*)d_in[15], (const float*)d_in[24], 1,
           nullptr, 0, 0, true, 0, 64);
  k_scan_part<<<dim3(1024), dim3(256), 0, stream>>>(Alog0, Alog1, dy2, (const unsigned short*)ub2, xdbc2, Hp, Pp);
  k_scan_comb<<<dim3(nb((size_t)BL2*NST)), dim3(256), 0, stream>>>(Hp, Pp);
  k_scan_fin<<<dim3(1024), dim3(256), 0, stream>>>(Alog0, Alog1, dy2, (const unsigned short*)ub2, xdbc2, Pp, zb, Dp0, Dp1, yb2);
  gemm_big(yb2, DI, 0, 0, w_out2, (size_t)CCH*DI, fob, nullptr, 0, DI, 0,
           BL2, CCH, DI, DI, 1, nullptr, nullptr, 0, nullptr, BL, 512, true, 0, 64);

  // --- final projection + bias + mask -> d_out (f32) ---
  gemm_big(fob, DI, 0, 0, w_proj, 0, d_out, nullptr, 0, CCH, 0,
           BL, CCH, DI, DI, 1, projb, projb, 0, m, 0, 0, false, 0, 64);
}

// Round 26
// 298.710 us; speedup vs baseline: 1.0711x; 1.0071x over previous
//
#include <hip/hip_runtime.h>
#include <hip/hip_bf16.h>

typedef __attribute__((ext_vector_type(8))) short short8;
typedef __attribute__((ext_vector_type(4))) float f32x4;
typedef __attribute__((ext_vector_type(4))) unsigned short ushort4_t;

#define BSZ 4
#define LSEQ 1024
#define CCH 512
#define BL (BSZ*LSEQ)   // 4096 rows
#define BL2 (2*BL)      // both directions batched: 8192 rows
#define DI 1024         // d_inner
#define NST 16
#define DTR 32
#define NCH 32          // scan chunks
#define CLEN 32         // chunk length (NCH*CLEN == LSEQ)

__device__ __forceinline__ float sigmoidf_(float x){ return 1.f/(1.f+__expf(-x)); }
// fast softplus: v_exp + add + v_log -- the OCML log1pf path is ~30 VALU inst (R14 lesson)
__device__ __forceinline__ float softplus_(float x){ return x > 20.f ? x : __logf(1.f + __expf(x)); }
__device__ __forceinline__ float fexp2_(float x){ return __builtin_amdgcn_exp2f(x); }  // raw v_exp_f32
__device__ __forceinline__ unsigned short f2bf_(float f){
  __hip_bfloat16 h = __float2bfloat16(f); return *(unsigned short*)&h;
}
__device__ __forceinline__ float b2f_(unsigned short s){
  unsigned u = ((unsigned)s) << 16; float f; __builtin_memcpy(&f, &u, 4); return f;
}

typedef const __attribute__((address_space(1))) unsigned int* gas_t;
typedef __attribute__((address_space(3))) unsigned int* las_t;
__device__ __forceinline__ void gload16(const void* g, void* l){
  __builtin_amdgcn_global_load_lds((gas_t)g, (las_t)l, 16, 0, 0);
}

// ---------------- unified prep kernel (R26): convw-prep + 9 casts + embed in ONE launch ----------------
// All three prologue kernels are independent & memory-bound; merging removes 2 launch
// overheads + serial BW tails. Bodies are verbatim from the R25 kernels.
struct CastEnt { const float* s; unsigned short* d; unsigned n4, acc; };
struct PrepArgs {
  CastEnt e[9]; unsigned total4;
  const float* cw; __hip_bfloat16* wt;                 // conv weight prep
  const int* x; const float* emb;                      // embed
  __hip_bfloat16* xpad0; __hip_bfloat16* xpad1;
  unsigned nbConvw, nbCast;                            // block-range boundaries
};
__global__ void k_prep_all(PrepArgs a){
  unsigned blk = blockIdx.x;
  if (blk < a.nbConvw){
    // conv_w [3][512][512][5] -> wt [3][512][2560], j = k*512 + ci
    int i = blk*256 + threadIdx.x;
    const int total = 3*CCH*CCH*5;
    if (i >= total) return;
    int j = i % (CCH*5);
    int co = (i/(CCH*5)) % CCH;
    int layer = i/(CCH*5*CCH);
    int k = j >> 9, ci = j & 511;
    a.wt[i] = __float2bfloat16(a.cw[(((size_t)layer*CCH + co)*CCH + ci)*5 + k]);
    return;
  }
  if (blk < a.nbConvw + a.nbCast){
    // 9 f32->bf16 weight casts via region table
    unsigned i = (blk - a.nbConvw)*256 + threadIdx.x;
    if (i >= a.total4) return;
    #pragma unroll
    for (int k=0;k<9;k++){
      if (i < a.e[k].acc + a.e[k].n4){
        unsigned j = i - a.e[k].acc;
        float4 v = ((const float4*)a.e[k].s)[j];
        ushort4_t o = { f2bf_(v.x), f2bf_(v.y), f2bf_(v.z), f2bf_(v.w) };
        *(ushort4_t*)(a.e[k].d + (size_t)j*4) = o;
        return;
      }
    }
    return;
  }
  // gather emb[x] into padded [B][L+4][C] bf16; tail range zeroes xpad1's 4 pad rows
  int i = (blk - a.nbConvw - a.nbCast)*256 + threadIdx.x;
  const int total = BSZ*(LSEQ+4)*CCH;
  const int total2 = total + BSZ*4*CCH;
  if (i >= total2) return;
  if (i >= total){
    int j = i - total;
    int c = j & (CCH-1);
    int pr = (j >> 9) & 3;
    int b = j >> 11;
    int rr = (pr < 2) ? pr : (LSEQ+2) + (pr-2);
    a.xpad1[((size_t)b*(LSEQ+4) + rr)*CCH + c] = __float2bfloat16(0.f);
    return;
  }
  int c = i & (CCH-1);
  int r = (i >> 9) % (LSEQ+4);
  int b = i / ((LSEQ+4)*CCH);
  float v = 0.f;
  if (r >= 2 && r < LSEQ+2){
    int tok = a.x[b*LSEQ + (r-2)];
    v = a.emb[(size_t)tok*CCH + c];
  }
  a.xpad0[i] = __float2bfloat16(v);
}

// per-(b,l) channel LayerNorm over bf16 (in + in2) + scale/shift + LeakyReLU(0.2) + mask
__global__ __launch_bounds__(256) void k_ln(
    const unsigned short* __restrict__ in, const unsigned short* __restrict__ in2,
    const float* __restrict__ g, const float* __restrict__ bb,
    const unsigned char* __restrict__ mask,
    __hip_bfloat16* __restrict__ xpad_next,
    __hip_bfloat16* __restrict__ h_enc){
  int row = blockIdx.x;                 // b*1024 + l
  int b = row >> 10, l = row & 1023;
  size_t ro = (size_t)row*CCH;
  int t = threadIdx.x;
  float v0 = b2f_(in[ro+t]) + b2f_(in2[ro+t]);
  float v1 = b2f_(in[ro+t+256]) + b2f_(in2[ro+t+256]);
  float s = v0+v1, s2 = v0*v0 + v1*v1;
  #pragma unroll
  for (int off=32; off>0; off>>=1){ s += __shfl_down(s,off); s2 += __shfl_down(s2,off); }
  __shared__ float ls[8];
  if ((t&63)==0){ ls[t>>6] = s; ls[(t>>6)+4] = s2; }
  __syncthreads();
  float S  = ls[0]+ls[1]+ls[2]+ls[3];
  float S2 = ls[4]+ls[5]+ls[6]+ls[7];
  float mu = S*(1.f/CCH);
  float var = S2*(1.f/CCH) - mu*mu;
  float rs = rsqrtf(var + 1e-5f);
  bool mk = mask[row] != 0;
  #pragma unroll
  for (int e=0; e<2; e++){
    int c = t + e*256;
    float v = e ? v1 : v0;
    float h = (v-mu)*rs*g[c] + bb[c];
    h = h > 0.f ? h : 0.2f*h;
    if (mk) h = 0.f;
    __hip_bfloat16 hb = __float2bfloat16(h);
    if (xpad_next) xpad_next[((size_t)b*(LSEQ+4) + (l+2))*CCH + c] = hb;
    if (h_enc) h_enc[(size_t)row*CCH + c] = hb;
  }
}

// ---------------- K-split GEMM for skinny N=64 (x_proj), batched dirs ----------------
// 16 rows per block; 4 waves each own a K/4 slice; LDS reduce.
__global__ __launch_bounds__(256) void k_gemm_ksplit(
    const __hip_bfloat16* __restrict__ A, int lda,
    const __hip_bfloat16* __restrict__ W, size_t wStride,
    float* __restrict__ Cout, int ldc, int K, unsigned short* __restrict__ dtb){
  __shared__ float red[4*1024];   // 16 KB
  int m0 = blockIdx.x << 4;
  const __hip_bfloat16* Wd = W + (size_t)(m0 >> 12)*wStride;
  int tid = threadIdx.x;
  int w = tid >> 6, lane = tid & 63;
  int r = lane & 15, kg = lane >> 4;
  int Kw = K >> 2;
  int kbase = w*Kw;

  const short* Ap = (const short*)A + (size_t)(m0 + r)*lda + kbase + kg*8;
  const short* Wp[4];
  #pragma unroll
  for (int nj=0; nj<4; nj++)
    Wp[nj] = (const short*)Wd + (size_t)(nj*16 + r)*K + kbase + kg*8;

  f32x4 acc[4];
  #pragma unroll
  for (int nj=0;nj<4;nj++) acc[nj] = (f32x4){0.f,0.f,0.f,0.f};

  for (int kk=0; kk<Kw; kk+=32){
    short8 a = *(const short8*)(Ap + kk);
    #pragma unroll
    for (int nj=0;nj<4;nj++){
      short8 wv = *(const short8*)(Wp[nj] + kk);
      acc[nj] = __builtin_amdgcn_mfma_f32_16x16x32_bf16(a, wv, acc[nj], 0,0,0);
    }
  }
  #pragma unroll
  for (int nj=0;nj<4;nj++)
    #pragma unroll
    for (int reg=0; reg<4; reg++){
      int rowt = kg*4 + reg;
      int col  = nj*16 + r;
      red[w*1024 + rowt*64 + col] = acc[nj][reg];
    }
  __syncthreads();
  int e0 = tid*4;
  f32x4 s = *(const f32x4*)&red[e0];
  #pragma unroll
  for (int ww=1; ww<4; ww++){
    f32x4 p = *(const f32x4*)&red[ww*1024 + e0];
    s.x += p.x; s.y += p.y; s.z += p.z; s.w += p.w;
  }
  int rowt = e0 >> 6, col = e0 & 63;
  *(f32x4*)&Cout[(size_t)(m0+rowt)*ldc + col] = s;
  if (col < 32){
    ushort4_t o = { f2bf_(s.x), f2bf_(s.y), f2bf_(s.z), f2bf_(s.w) };
    *(ushort4_t*)&dtb[(size_t)(m0+rowt)*32 + col] = o;
  }
}

// ---------------- big staged GEMM: 128(M)xBN(N) tile, BK=32, 4 waves ----------------
// BN=64 (proven R15/R20/R22 path): wave = 64x32 quadrant, 8 MFMA/step, 36KB, 4 blk/CU.
// BN=128 (R23-proven, in_proj only): wave = 64x64 quadrant, 16 MFMA/step, 48KB, 3 blk/CU
//   -- 2x MFMA-per-barrier at only -25% occupancy; pays only at in_proj's 1024-block grid
//   (R24: transferring to conv regressed -- grid/partial-traffic conditions not met).
// Ring-3, depth-2 prefetch, counted vmcnt(G), parity swizzle, XCD remap,
// nSeg K-split (seg s -> C0 + s*segBytes, bias on seg 0), uzMode, revA, per-dir bias.
template<bool OUTBF, int BN>
__global__ __launch_bounds__(256) void k_gemm_big(
    const __hip_bfloat16* __restrict__ A, int lda, int padExtra, int revA,
    const __hip_bfloat16* __restrict__ W, size_t wStride,
    void* __restrict__ C0, void* __restrict__ C1, size_t segBytes, int ldc, int coloff,
    int tiles_n, int baseBlocks, int totalBlocks, int Kc, int Kb,
    const float* __restrict__ bias0, const float* __restrict__ bias1, int act,
    const unsigned char* __restrict__ mask, int outRowSub, int dirColOff, int uzMode){
  constexpr int NJ = BN/32;                 // fragments per wave in N (2 or 4)
  constexpr int BUFE = 4096 + BN*32;        // elements per ring buffer
  __shared__ alignas(16) __hip_bfloat16 smem[3][BUFE];
  int b = blockIdx.x;
  int wg = (b & 7)*(totalBlocks >> 3) + (b >> 3);        // XCD-contiguous remap
  int seg = wg / baseBlocks;
  int bid = wg - seg*baseBlocks;
  int tn = bid % tiles_n;
  int tm = bid / tiles_n;
  int m0 = tm*128, n0 = tn*BN;
  int dir = m0 >> 12;
  int kOff = seg*Kc;
  const __hip_bfloat16* Wd = W + (size_t)dir*wStride;
  void* Cout = (void*)((char*)C0 + (size_t)seg*segBytes);
  const float* bsel = dir ? bias1 : bias0;
  const float* biasp = (bsel && seg==0) ? bsel : nullptr;

  int tid = threadIdx.x;
  int wid = tid >> 6, lane = tid & 63;
  int r = lane & 15, kg = lane >> 4;

  int sr = lane >> 2;
  int gs = (lane & 3) ^ ((sr >> 1) & 3);
  auto physrow = [&](int ar)->int{
    if (revA && ar >= 4096){
      int r2 = ar - 4096;
      return (r2 & ~1023) | (1023 - (r2 & 1023));
    }
    return ar + padExtra*(ar >> 10);
  };
  int arow0 = m0 + wid*16 + sr;
  int arow1 = arow0 + 64;
  size_t aoff0 = (size_t)physrow(arow0)*lda + kOff + gs*8;
  size_t aoff1 = (size_t)physrow(arow1)*lda + kOff + gs*8;
  size_t boffq[BN/64];
  #pragma unroll
  for (int q=0; q<BN/64; q++){
    int bcol = n0 + wid*16 + q*64 + sr;
    boffq[q] = (size_t)bcol*Kb + kOff + gs*8;
  }

  int wr = wid >> 1, wc = wid & 1;
  int xs = (kg ^ ((r >> 1) & 3))*8;
  int afrag[4], bfrag[NJ];
  #pragma unroll
  for (int mi=0; mi<4; mi++) afrag[mi] = (wr*64 + mi*16 + r)*32 + xs;
  #pragma unroll
  for (int nj=0; nj<NJ; nj++) bfrag[nj] = 4096 + (wc*(BN/2) + nj*16 + r)*32 + xs;

  f32x4 acc[4][NJ];
  #pragma unroll
  for (int mi=0;mi<4;mi++)
    #pragma unroll
    for (int nj=0;nj<NJ;nj++) acc[mi][nj] = (f32x4){0.f,0.f,0.f,0.f};

  const int nt = Kc >> 5;
  auto stage = [&](int kt, int bufi){
    __hip_bfloat16* sb = &smem[bufi][0];
    int k0 = kt*32;
    gload16((const short*)A + aoff0 + k0, sb + wid*512);
    gload16((const short*)A + aoff1 + k0, sb + (wid+4)*512);
    #pragma unroll
    for (int q=0; q<BN/64; q++)
      gload16((const short*)W + (size_t)(Wd - W) + boffq[q] + k0, sb + 4096 + (q*4 + wid)*512);
  };
  auto compute = [&](int bufi){
    const __hip_bfloat16* sb = &smem[bufi][0];
    short8 a[4], bb2[NJ];
    #pragma unroll
    for (int mi=0;mi<4;mi++) a[mi] = *(const short8*)&sb[afrag[mi]];
    #pragma unroll
    for (int nj=0;nj<NJ;nj++) bb2[nj] = *(const short8*)&sb[bfrag[nj]];
    #pragma unroll
    for (int mi=0;mi<4;mi++)
      #pragma unroll
      for (int nj=0;nj<NJ;nj++)
        acc[mi][nj] = __builtin_amdgcn_mfma_f32_16x16x32_bf16(a[mi], bb2[nj], acc[mi][nj], 0,0,0);
  };

  if (nt >= 3){
    stage(0, 0);
    stage(1, 1);
    int bi = 0;
    #pragma unroll 1
    for (int t=0; t<nt; t++){
      if (t+1 < nt){
        if constexpr (BN == 64) asm volatile("s_waitcnt vmcnt(3)" ::: "memory");
        else                    asm volatile("s_waitcnt vmcnt(4)" ::: "memory");
      } else {
        asm volatile("s_waitcnt vmcnt(0)" ::: "memory");
      }
      __builtin_amdgcn_s_barrier();
      __builtin_amdgcn_sched_barrier(0);
      if (t+2 < nt){
        int nb2 = bi + 2; if (nb2 >= 3) nb2 -= 3;
        stage(t+2, nb2);
      }
      compute(bi);
      bi = (bi+1 == 3) ? 0 : bi+1;
    }
  } else {
    for (int s=0; s<nt; s++) stage(s, s);
    asm volatile("s_waitcnt vmcnt(0)" ::: "memory");
    __builtin_amdgcn_s_barrier();
    __builtin_amdgcn_sched_barrier(0);
    for (int t=0; t<nt; t++) compute(t);
  }

  #pragma unroll
  for (int mi=0;mi<4;mi++){
    #pragma unroll
    for (int nj=0;nj<NJ;nj++){
      #pragma unroll
      for (int reg=0; reg<4; reg++){
        int row = m0 + wr*64 + mi*16 + kg*4 + reg;
        int col = n0 + wc*(BN/2) + nj*16 + r;
        float v = acc[mi][nj][reg];
        if (uzMode){
          if (col < 1024) ((__hip_bfloat16*)C0)[(size_t)row*1024 + col] = __float2bfloat16(v);
          else            ((__hip_bfloat16*)C1)[(size_t)row*1024 + (col-1024)] = __float2bfloat16(v);
          continue;
        }
        if (biasp) v += biasp[col];
        if (act == 1) v = softplus_(v);
        int row_out = row - dir*outRowSub;
        if (mask && mask[row_out]) v = 0.f;
        size_t o = (size_t)row_out*ldc + coloff + dir*dirColOff + col;
        if (OUTBF) ((__hip_bfloat16*)Cout)[o] = __float2bfloat16(v);
        else       ((float*)Cout)[o] = v;
      }
    }
  }
}

// ---------------- mamba pieces (batched: rows 0..8191, dir = row>>12) ----------------

// depthwise conv over bf16 u_pre -> bf16 ub only
__global__ void k_dwconv(const unsigned short* __restrict__ upre,
                         const float* __restrict__ cw0, const float* __restrict__ cw1,
                         const float* __restrict__ cb0, const float* __restrict__ cb1,
                         __hip_bfloat16* __restrict__ ub){
  int i = blockIdx.x*256 + threadIdx.x;     // over BL2*DI/4
  if (i >= BL2*DI/4) return;
  int d4 = i & (DI/4 - 1);
  int d = d4 << 2;
  int row = i >> 8;
  int dir = row >> 12;
  const float* cw = (dir ? cw1 : cw0) + d*4;
  const float* cb = (dir ? cb1 : cb0) + d;
  int l = row & 1023;
  int rb = row & ~1023;
  f32x4 cwv[4];
  #pragma unroll
  for (int j=0;j<4;j++) cwv[j] = *(const f32x4*)&cw[j*4];
  f32x4 acc = *(const f32x4*)cb;
  #pragma unroll
  for (int k=0;k<4;k++){
    int ll = l - 3 + k;
    if (ll >= 0){
      ushort4_t xv = *(const ushort4_t*)&upre[(size_t)(rb + ll)*DI + d];
      acc.x = __fmaf_rn(cwv[0][k], b2f_(xv.x), acc.x);
      acc.y = __fmaf_rn(cwv[1][k], b2f_(xv.y), acc.y);
      acc.z = __fmaf_rn(cwv[2][k], b2f_(xv.z), acc.z);
      acc.w = __fmaf_rn(cwv[3][k], b2f_(xv.w), acc.w);
    }
  }
  f32x4 s;
  s.x = acc.x * sigmoidf_(acc.x);
  s.y = acc.y * sigmoidf_(acc.y);
  s.z = acc.z * sigmoidf_(acc.z);
  s.w = acc.w * sigmoidf_(acc.w);
  ushort4_t o = { f2bf_(s.x), f2bf_(s.y), f2bf_(s.z), f2bf_(s.w) };
  *(ushort4_t*)((unsigned short*)ub + (size_t)i*4) = o;
}

// -------- chunked selective scan, thread-per-d, both dirs in one dispatch --------
// Af prescaled by log2(e); dA via __builtin_amdgcn_exp2f (single v_exp_f32).
// dv/uv(/zv) streams software-pipelined in groups of 8; dv,u,z all read as bf16.

__global__ __launch_bounds__(256) void k_scan_part(
    const float* __restrict__ Alog0, const float* __restrict__ Alog1,
    const unsigned short* __restrict__ dyb, const unsigned short* __restrict__ ub,
    const float* __restrict__ xdbc,
    float* __restrict__ Hp, float* __restrict__ Pp){
  __shared__ alignas(16) float Bsh[CLEN*16];
  int t = threadIdx.x;
  int dblk = blockIdx.x & 3;
  int c = (blockIdx.x >> 2) & (NCH-1);
  int b8 = blockIdx.x >> 7;
  const float* A_log = (b8 >> 2) ? Alog1 : Alog0;
  int d = dblk*256 + t;
  size_t blbase = (size_t)b8*LSEQ + (size_t)c*CLEN;
  if (t < CLEN*4){
    int l = t >> 2, q = t & 3;
    *(f32x4*)&Bsh[l*16 + q*4] = *(const f32x4*)&xdbc[(blbase+l)*64 + 32 + q*4];
  }
  float Af[16];
  #pragma unroll
  for (int n=0; n<16; n+=4){
    f32x4 a = *(const f32x4*)&A_log[(size_t)d*16 + n];
    Af[n]   = -__expf(a.x)*1.442695041f; Af[n+1] = -__expf(a.y)*1.442695041f;
    Af[n+2] = -__expf(a.z)*1.442695041f; Af[n+3] = -__expf(a.w)*1.442695041f;
  }
  float h[16];
  #pragma unroll
  for (int n=0;n<16;n++) h[n]=0.f;
  float Sdv = 0.f;
  const unsigned short* dyp = dyb + blbase*DI + d;
  const unsigned short* ubp = ub + blbase*DI + d;
  float dvb[2][8], uvb[2][8];
  #pragma unroll
  for (int j=0;j<8;j++){ dvb[0][j] = b2f_(dyp[(size_t)j*DI]); uvb[0][j] = b2f_(ubp[(size_t)j*DI]); }
  __syncthreads();
  #pragma unroll
  for (int g=0; g<4; g++){
    int cur = g & 1;
    if (g+1 < 4){
      int nxt = cur ^ 1;
      #pragma unroll
      for (int j=0;j<8;j++){
        size_t l = (size_t)(g+1)*8 + j;
        dvb[nxt][j] = b2f_(dyp[l*DI]); uvb[nxt][j] = b2f_(ubp[l*DI]);
      }
    }
    #pragma unroll
    for (int j=0;j<8;j++){
      int l = g*8 + j;
      float dv = dvb[cur][j], uv = uvb[cur][j];
      float duv = dv*uv;
      Sdv += dv;
      #pragma unroll
      for (int n=0;n<16;n++){
        float dA = fexp2_(dv*Af[n]);
        h[n] = __fmaf_rn(dA, h[n], duv*Bsh[l*16+n]);
      }
    }
  }
  size_t pb = (((size_t)(b8*NCH + c))*DI + d)*16;
  #pragma unroll
  for (int n=0;n<16;n+=4){
    *(f32x4*)&Hp[pb+n] = (f32x4){h[n],h[n+1],h[n+2],h[n+3]};
    *(f32x4*)&Pp[pb+n] = (f32x4){fexp2_(Af[n]*Sdv), fexp2_(Af[n+1]*Sdv),
                                 fexp2_(Af[n+2]*Sdv), fexp2_(Af[n+3]*Sdv)};
  }
}

// combine: h_in[c+1] = P[c]*h_in[c] + H[c]; writes h_in back into Pp (in place)
__global__ void k_scan_comb(float* __restrict__ Hp, float* __restrict__ Pp){
  int i = blockIdx.x*256 + threadIdx.x;   // (row8k)*16 + n
  if (i >= BL2*NST) return;
  int n = i & 15, row = i >> 4;
  int b8 = row >> 10, d = row & 1023;
  float hin = 0.f;
  #pragma unroll
  for (int c=0;c<NCH;c++){
    size_t idx = (((size_t)(b8*NCH + c))*DI + d)*16 + n;
    float P = Pp[idx], H = Hp[idx];
    Pp[idx] = hin;
    hin = __fmaf_rn(P, hin, H);
  }
}

// final pass: recompute chunk states from h_in, emit y fused with ygate -> yb (bf16)
__global__ __launch_bounds__(256) void k_scan_fin(
    const float* __restrict__ Alog0, const float* __restrict__ Alog1,
    const unsigned short* __restrict__ dyb, const unsigned short* __restrict__ ub,
    const float* __restrict__ xdbc,
    const float* __restrict__ Hin, const unsigned short* __restrict__ zb,
    const float* __restrict__ Dp0, const float* __restrict__ Dp1,
    __hip_bfloat16* __restrict__ yb){
  __shared__ alignas(16) float BCsh[CLEN*32];
  int t = threadIdx.x;
  int dblk = blockIdx.x & 3;
  int c = (blockIdx.x >> 2) & (NCH-1);
  int b8 = blockIdx.x >> 7;
  int dirb = b8 >> 2;
  const float* A_log = dirb ? Alog1 : Alog0;
  const float* Dp = dirb ? Dp1 : Dp0;
  int d = dblk*256 + t;
  size_t blbase = (size_t)b8*LSEQ + (size_t)c*CLEN;
  {
    int l = t >> 3, q = t & 7;
    *(f32x4*)&BCsh[l*32 + q*4] = *(const f32x4*)&xdbc[(blbase+l)*64 + 32 + q*4];
  }
  float Af[16];
  #pragma unroll
  for (int n=0; n<16; n+=4){
    f32x4 a = *(const f32x4*)&A_log[(size_t)d*16 + n];
    Af[n]   = -__expf(a.x)*1.442695041f; Af[n+1] = -__expf(a.y)*1.442695041f;
    Af[n+2] = -__expf(a.z)*1.442695041f; Af[n+3] = -__expf(a.w)*1.442695041f;
  }
  size_t pb = (((size_t)(b8*NCH + c))*DI + d)*16;
  float h[16];
  #pragma unroll
  for (int n=0;n<16;n+=4){
    f32x4 hv = *(const f32x4*)&Hin[pb+n];
    h[n]=hv.x; h[n+1]=hv.y; h[n+2]=hv.z; h[n+3]=hv.w;
  }
  float Dd = Dp[d];
  const unsigned short* dyp = dyb + blbase*DI + d;
  const unsigned short* ubp = ub + blbase*DI + d;
  const unsigned short* zp  = zb + blbase*DI + d;
  float dvb[2][8], uvb[2][8], zvb[2][8];
  #pragma unroll
  for (int j=0;j<8;j++){
    dvb[0][j] = b2f_(dyp[(size_t)j*DI]);
    uvb[0][j] = b2f_(ubp[(size_t)j*DI]);
    zvb[0][j] = b2f_(zp[(size_t)j*DI]);
  }
  __syncthreads();
  #pragma unroll
  for (int g=0; g<4; g++){
    int cur = g & 1;
    if (g+1 < 4){
      int nxt = cur ^ 1;
      #pragma unroll
      for (int j=0;j<8;j++){
        size_t l = (size_t)(g+1)*8 + j;
        dvb[nxt][j] = b2f_(dyp[l*DI]);
        uvb[nxt][j] = b2f_(ubp[l*DI]);
        zvb[nxt][j] = b2f_(zp[l*DI]);
      }
    }
    #pragma unroll
    for (int j=0;j<8;j++){
      int l = g*8 + j;
      float dv = dvb[cur][j], uv = uvb[cur][j], zv = zvb[cur][j];
      float duv = dv*uv;
      float y = 0.f;
      #pragma unroll
      for (int n=0;n<16;n++){
        float dA = fexp2_(dv*Af[n]);
        h[n] = __fmaf_rn(dA, h[n], duv*BCsh[l*32+n]);
        y = __fmaf_rn(h[n], BCsh[l*32+16+n], y);
      }
      float gg = zv * sigmoidf_(zv);
      float out = __fmaf_rn(uv, Dd, y) * gg;
      yb[(blbase+l)*DI + d] = __float2bfloat16(out);
    }
  }
}

// ---------------- host ----------------

extern "C" void kernel_launch(void* const* d_in, const int* in_sizes, int n_in,
                              void* d_out, int out_size, void* d_ws, size_t ws_size,
                              hipStream_t stream){
  (void)in_sizes; (void)n_in; (void)out_size; (void)ws_size;
  const int*   x     = (const int*)d_in[0];
  const unsigned char* m = (const unsigned char*)d_in[2];
  const float* emb   = (const float*)d_in[3];
  const float* convw = (const float*)d_in[4];
  const float* convb = (const float*)d_in[5];
  const float* lng   = (const float*)d_in[6];
  const float* lnb   = (const float*)d_in[7];
  const float* projw = (const float*)d_in[8];
  const float* projb = (const float*)d_in[9];

  char* ws = (char*)d_ws;
  size_t off = 0;
  auto alloc = [&](size_t bytes)->char*{
    char* p = ws + off; off += (bytes + 255) & ~((size_t)255); return p;
  };
  auto wt_conv = (__hip_bfloat16*)alloc((size_t)3*CCH*CCH*5*2);
  auto w_in2  = (__hip_bfloat16*)alloc((size_t)2*2*DI*CCH*2);
  auto w_x2   = (__hip_bfloat16*)alloc((size_t)2*64*DI*2);
  auto w_dt2  = (__hip_bfloat16*)alloc((size_t)2*DI*DTR*2);
  auto w_out2 = (__hip_bfloat16*)alloc((size_t)2*CCH*DI*2);
  auto w_proj = (__hip_bfloat16*)alloc((size_t)CCH*1024*2);
  auto xpad0  = (__hip_bfloat16*)alloc((size_t)BSZ*(LSEQ+4)*CCH*2);
  auto xpad1  = (__hip_bfloat16*)alloc((size_t)BSZ*(LSEQ+4)*CCH*2);
  auto scr    = (float*)alloc((size_t)8*NCH*DI*NST*4);   // 16.78 MB: conv partial0 (bf16) / scan Hp
  auto h_enc  = (__hip_bfloat16*)alloc((size_t)BL*CCH*2);
  auto upre   = (unsigned short*)alloc((size_t)BL2*DI*2);  // in_proj u-half, bf16
  auto zb     = (unsigned short*)alloc((size_t)BL2*DI*2);  // in_proj z-half, bf16
  auto ub2    = (__hip_bfloat16*)alloc((size_t)BL2*DI*2);  // conv'd u, bf16
  auto xdbc2  = (float*)alloc((size_t)BL2*64*4);
  auto dtb2   = (unsigned short*)alloc((size_t)BL2*DTR*2);
  auto dy2    = (unsigned short*)alloc((size_t)BL2*DI*2);  // delta bf16
  auto convp1 = (unsigned short*)alloc((size_t)BL*CCH*2);  // conv partial1 (bf16, encoder only)
  auto yb2    = (__hip_bfloat16*)alloc((size_t)BL2*DI*2);
  auto fob    = (__hip_bfloat16*)alloc((size_t)BL*DI*2);
  auto Pp     = (float*)alloc((size_t)8*NCH*DI*NST*4);

  float* Hp = scr;

  auto nb = [](size_t n){ return (unsigned)((n + 255)/256); };

  // --- unified weight prep + embed: one dispatch (R26) ---
  {
    PrepArgs pa;
    unsigned acc = 0;
    auto put = [&](int k, const void* s, void* d, unsigned n4){
      pa.e[k].s = (const float*)s; pa.e[k].d = (unsigned short*)d;
      pa.e[k].n4 = n4; pa.e[k].acc = acc; acc += n4;
    };
    for (int dir=0; dir<2; dir++){
      int base = 10 + 9*dir;
      put(dir*4+0, d_in[base+0], (unsigned short*)w_in2  + (size_t)dir*2*DI*CCH, (2*DI*CCH)/4);
      put(dir*4+1, d_in[base+3], (unsigned short*)w_x2   + (size_t)dir*64*DI,    (64*DI)/4);
      put(dir*4+2, d_in[base+4], (unsigned short*)w_dt2  + (size_t)dir*DI*DTR,   (DI*DTR)/4);
      put(dir*4+3, d_in[base+8], (unsigned short*)w_out2 + (size_t)dir*CCH*DI,   (CCH*DI)/4);
    }
    put(8, projw, w_proj, (CCH*1024)/4);
    pa.total4 = acc;
    pa.cw = convw; pa.wt = wt_conv;
    pa.x = x; pa.emb = emb; pa.xpad0 = xpad0; pa.xpad1 = xpad1;
    pa.nbConvw = nb((size_t)3*CCH*CCH*5);
    pa.nbCast  = nb(acc);
    unsigned nbEmbed = nb((size_t)BSZ*(LSEQ+4)*CCH + BSZ*4*CCH);
    k_prep_all<<<dim3(pa.nbConvw + pa.nbCast + nbEmbed), dim3(256), 0, stream>>>(pa);
  }

  auto gemm_big = [&](const void* A, int lda, int padE, int revA, const void* W, size_t wStride,
                  void* C0, void* C1, size_t segBytes, int ldc, int coloff,
                  int M, int N, int Kc, int Kb, int nSeg,
                  const float* bias0, const float* bias1, int act,
                  const unsigned char* msk, int outRowSub, int dirColOff, bool outbf, int uzMode,
                  int bn){
    int tiles_n = N/bn;
    int baseBlocks = (M/128)*tiles_n;
    int blocks = baseBlocks * nSeg;
    if (bn == 128){
      if (outbf)
        k_gemm_big<true,128><<<dim3(blocks), dim3(256), 0, stream>>>((const __hip_bfloat16*)A, lda, padE, revA,
            (const __hip_bfloat16*)W, wStride, C0, C1, segBytes, ldc, coloff, tiles_n, baseBlocks, blocks,
            Kc, Kb, bias0, bias1, act, msk, outRowSub, dirColOff, uzMode);
      else
        k_gemm_big<false,128><<<dim3(blocks), dim3(256), 0, stream>>>((const __hip_bfloat16*)A, lda, padE, revA,
            (const __hip_bfloat16*)W, wStride, C0, C1, segBytes, ldc, coloff, tiles_n, baseBlocks, blocks,
            Kc, Kb, bias0, bias1, act, msk, outRowSub, dirColOff, uzMode);
    } else {
      if (outbf)
        k_gemm_big<true,64><<<dim3(blocks), dim3(256), 0, stream>>>((const __hip_bfloat16*)A, lda, padE, revA,
            (const __hip_bfloat16*)W, wStride, C0, C1, segBytes, ldc, coloff, tiles_n, baseBlocks, blocks,
            Kc, Kb, bias0, bias1, act, msk, outRowSub, dirColOff, uzMode);
      else
        k_gemm_big<false,64><<<dim3(blocks), dim3(256), 0, stream>>>((const __hip_bfloat16*)A, lda, padE, revA,
            (const __hip_bfloat16*)W, wStride, C0, C1, segBytes, ldc, coloff, tiles_n, baseBlocks, blocks,
            Kc, Kb, bias0, bias1, act, msk, outRowSub, dirColOff, uzMode);
    }
  };

  // --- encoder: 3x (conv-as-GEMM BN=64 2-way K-split, bf16 partials -> LN) ---
  __hip_bfloat16* xp_in = xpad0;
  __hip_bfloat16* xp_out = xpad1;
  const size_t segB_conv = (size_t)((char*)convp1 - (char*)scr);   // seg1 -> convp1
  for (int layer=0; layer<3; layer++){
    const __hip_bfloat16* wt = wt_conv + (size_t)layer*CCH*CCH*5;
    gemm_big(xp_in, CCH, 4, 0, wt, 0, scr, nullptr, segB_conv, CCH, 0, BL, CCH, 1280, 2560, 2,
             convb + layer*CCH, convb + layer*CCH, 0, nullptr, 0, 0, true, 0, 64);
    bool last = (layer==2);
    k_ln<<<dim3(BL), dim3(256), 0, stream>>>((const unsigned short*)scr, convp1,
        lng + layer*CCH, lnb + layer*CCH, m,
        last ? nullptr : xp_out, last ? h_enc : nullptr);
    __hip_bfloat16* t2 = xp_in; xp_in = xp_out; xp_out = t2;
  }

  // --- bidirectional mamba, both directions batched (rows 0..8191, dir = row>>12);
  //     dir-1 reads h_enc reversed via revA (no materialized h_rev) ---
  const float* Alog0 = (const float*)d_in[16];
  const float* Alog1 = (const float*)d_in[25];
  const float* Dp0   = (const float*)d_in[17];
  const float* Dp1   = (const float*)d_in[26];

  // in_proj: BN=128 (R23-proven: 1024 blocks, 48KB ring-3, 16 MFMA/wave/step)
  gemm_big(h_enc, CCH, 0, 1, w_in2, (size_t)2*DI*CCH, upre, zb, 0, 2*DI, 0,
           BL2, 2*DI, CCH, CCH, 1, nullptr, nullptr, 0, nullptr, 0, 0, false, 1, 128);
  k_dwconv<<<dim3(nb((size_t)BL2*DI/4)), dim3(256), 0, stream>>>(upre,
      (const float*)d_in[11], (const float*)d_in[20],
      (const float*)d_in[12], (const float*)d_in[21], ub2);
  k_gemm_ksplit<<<dim3(BL2/16), dim3(256), 0, stream>>>(ub2, DI, w_x2, (size_t)64*DI, xdbc2, 64, DI, dtb2);
  gemm_big(dtb2, DTR, 0, 0, w_dt2, (size_t)DI*DTR, dy2, nullptr, 0, DI, 0,
           BL2, DI, DTR, DTR, 1, (const float*)d_in[15], (const float*)d_in[24], 1,
           nullptr, 0, 0, true, 0, 64);
  k_scan_part<<<dim3(1024), dim3(256), 0, stream>>>(Alog0, Alog1, dy2, (const unsigned short*)ub2, xdbc2, Hp, Pp);
  k_scan_comb<<<dim3(nb((size_t)BL2*NST)), dim3(256), 0, stream>>>(Hp, Pp);
  k_scan_fin<<<dim3(1024), dim3(256), 0, stream>>>(Alog0, Alog1, dy2, (const unsigned short*)ub2, xdbc2, Pp, zb, Dp0, Dp1, yb2);
  gemm_big(yb2, DI, 0, 0, w_out2, (size_t)CCH*DI, fob, nullptr, 0, DI, 0,
           BL2, CCH, DI, DI, 1, nullptr, nullptr, 0, nullptr, BL, 512, true, 0, 64);

  // --- final projection + bias + mask -> d_out (f32) ---
  gemm_big(fob, DI, 0, 0, w_proj, 0, d_out, nullptr, 0, CCH, 0,
           BL, CCH, DI, DI, 1, projb, projb, 0, m, 0, 0, false, 0, 64);
}

// Round 27
// 293.230 us; speedup vs baseline: 1.0911x; 1.0187x over previous
//
#include <hip/hip_runtime.h>
#include <hip/hip_bf16.h>

typedef __attribute__((ext_vector_type(8))) short short8;
typedef __attribute__((ext_vector_type(4))) float f32x4;
typedef __attribute__((ext_vector_type(4))) unsigned short ushort4_t;

#define BSZ 4
#define LSEQ 1024
#define CCH 512
#define BL (BSZ*LSEQ)   // 4096 rows
#define BL2 (2*BL)      // both directions batched: 8192 rows
#define DI 1024         // d_inner
#define NST 16
#define DTR 32
#define NCH 32          // scan chunks
#define CLEN 32         // chunk length (NCH*CLEN == LSEQ)

__device__ __forceinline__ float sigmoidf_(float x){ return 1.f/(1.f+__expf(-x)); }
// fast softplus: v_exp + add + v_log -- the OCML log1pf path is ~30 VALU inst (R14 lesson)
__device__ __forceinline__ float softplus_(float x){ return x > 20.f ? x : __logf(1.f + __expf(x)); }
__device__ __forceinline__ float fexp2_(float x){ return __builtin_amdgcn_exp2f(x); }  // raw v_exp_f32
__device__ __forceinline__ unsigned short f2bf_(float f){
  __hip_bfloat16 h = __float2bfloat16(f); return *(unsigned short*)&h;
}
__device__ __forceinline__ float b2f_(unsigned short s){
  unsigned u = ((unsigned)s) << 16; float f; __builtin_memcpy(&f, &u, 4); return f;
}

typedef const __attribute__((address_space(1))) unsigned int* gas_t;
typedef __attribute__((address_space(3))) unsigned int* las_t;
__device__ __forceinline__ void gload16(const void* g, void* l){
  __builtin_amdgcn_global_load_lds((gas_t)g, (las_t)l, 16, 0, 0);
}

// ---------------- unified prep kernel (R26): convw-prep + 9 casts + embed in ONE launch ----------------
struct CastEnt { const float* s; unsigned short* d; unsigned n4, acc; };
struct PrepArgs {
  CastEnt e[9]; unsigned total4;
  const float* cw; __hip_bfloat16* wt;                 // conv weight prep
  const int* x; const float* emb;                      // embed
  __hip_bfloat16* xpad0; __hip_bfloat16* xpad1;
  unsigned nbConvw, nbCast;                            // block-range boundaries
};
__global__ void k_prep_all(PrepArgs a){
  unsigned blk = blockIdx.x;
  if (blk < a.nbConvw){
    // conv_w [3][512][512][5] -> wt [3][512][2560], j = k*512 + ci
    int i = blk*256 + threadIdx.x;
    const int total = 3*CCH*CCH*5;
    if (i >= total) return;
    int j = i % (CCH*5);
    int co = (i/(CCH*5)) % CCH;
    int layer = i/(CCH*5*CCH);
    int k = j >> 9, ci = j & 511;
    a.wt[i] = __float2bfloat16(a.cw[(((size_t)layer*CCH + co)*CCH + ci)*5 + k]);
    return;
  }
  if (blk < a.nbConvw + a.nbCast){
    // 9 f32->bf16 weight casts via region table
    unsigned i = (blk - a.nbConvw)*256 + threadIdx.x;
    if (i >= a.total4) return;
    #pragma unroll
    for (int k=0;k<9;k++){
      if (i < a.e[k].acc + a.e[k].n4){
        unsigned j = i - a.e[k].acc;
        float4 v = ((const float4*)a.e[k].s)[j];
        ushort4_t o = { f2bf_(v.x), f2bf_(v.y), f2bf_(v.z), f2bf_(v.w) };
        *(ushort4_t*)(a.e[k].d + (size_t)j*4) = o;
        return;
      }
    }
    return;
  }
  // gather emb[x] into padded [B][L+4][C] bf16; tail range zeroes xpad1's 4 pad rows
  int i = (blk - a.nbConvw - a.nbCast)*256 + threadIdx.x;
  const int total = BSZ*(LSEQ+4)*CCH;
  const int total2 = total + BSZ*4*CCH;
  if (i >= total2) return;
  if (i >= total){
    int j = i - total;
    int c = j & (CCH-1);
    int pr = (j >> 9) & 3;
    int b = j >> 11;
    int rr = (pr < 2) ? pr : (LSEQ+2) + (pr-2);
    a.xpad1[((size_t)b*(LSEQ+4) + rr)*CCH + c] = __float2bfloat16(0.f);
    return;
  }
  int c = i & (CCH-1);
  int r = (i >> 9) % (LSEQ+4);
  int b = i / ((LSEQ+4)*CCH);
  float v = 0.f;
  if (r >= 2 && r < LSEQ+2){
    int tok = a.x[b*LSEQ + (r-2)];
    v = a.emb[(size_t)tok*CCH + c];
  }
  a.xpad0[i] = __float2bfloat16(v);
}

// per-(b,l) channel LayerNorm over bf16 (in + in2) + scale/shift + LeakyReLU(0.2) + mask
__global__ __launch_bounds__(256) void k_ln(
    const unsigned short* __restrict__ in, const unsigned short* __restrict__ in2,
    const float* __restrict__ g, const float* __restrict__ bb,
    const unsigned char* __restrict__ mask,
    __hip_bfloat16* __restrict__ xpad_next,
    __hip_bfloat16* __restrict__ h_enc){
  int row = blockIdx.x;                 // b*1024 + l
  int b = row >> 10, l = row & 1023;
  size_t ro = (size_t)row*CCH;
  int t = threadIdx.x;
  float v0 = b2f_(in[ro+t]) + b2f_(in2[ro+t]);
  float v1 = b2f_(in[ro+t+256]) + b2f_(in2[ro+t+256]);
  float s = v0+v1, s2 = v0*v0 + v1*v1;
  #pragma unroll
  for (int off=32; off>0; off>>=1){ s += __shfl_down(s,off); s2 += __shfl_down(s2,off); }
  __shared__ float ls[8];
  if ((t&63)==0){ ls[t>>6] = s; ls[(t>>6)+4] = s2; }
  __syncthreads();
  float S  = ls[0]+ls[1]+ls[2]+ls[3];
  float S2 = ls[4]+ls[5]+ls[6]+ls[7];
  float mu = S*(1.f/CCH);
  float var = S2*(1.f/CCH) - mu*mu;
  float rs = rsqrtf(var + 1e-5f);
  bool mk = mask[row] != 0;
  #pragma unroll
  for (int e=0; e<2; e++){
    int c = t + e*256;
    float v = e ? v1 : v0;
    float h = (v-mu)*rs*g[c] + bb[c];
    h = h > 0.f ? h : 0.2f*h;
    if (mk) h = 0.f;
    __hip_bfloat16 hb = __float2bfloat16(h);
    if (xpad_next) xpad_next[((size_t)b*(LSEQ+4) + (l+2))*CCH + c] = hb;
    if (h_enc) h_enc[(size_t)row*CCH + c] = hb;
  }
}

// ---------------- K-split GEMM for skinny N=64 (x_proj), batched dirs ----------------
// 16 rows per block; 4 waves each own a K/4 slice; LDS reduce.
__global__ __launch_bounds__(256) void k_gemm_ksplit(
    const __hip_bfloat16* __restrict__ A, int lda,
    const __hip_bfloat16* __restrict__ W, size_t wStride,
    float* __restrict__ Cout, int ldc, int K, unsigned short* __restrict__ dtb){
  __shared__ float red[4*1024];   // 16 KB
  int m0 = blockIdx.x << 4;
  const __hip_bfloat16* Wd = W + (size_t)(m0 >> 12)*wStride;
  int tid = threadIdx.x;
  int w = tid >> 6, lane = tid & 63;
  int r = lane & 15, kg = lane >> 4;
  int Kw = K >> 2;
  int kbase = w*Kw;

  const short* Ap = (const short*)A + (size_t)(m0 + r)*lda + kbase + kg*8;
  const short* Wp[4];
  #pragma unroll
  for (int nj=0; nj<4; nj++)
    Wp[nj] = (const short*)Wd + (size_t)(nj*16 + r)*K + kbase + kg*8;

  f32x4 acc[4];
  #pragma unroll
  for (int nj=0;nj<4;nj++) acc[nj] = (f32x4){0.f,0.f,0.f,0.f};

  for (int kk=0; kk<Kw; kk+=32){
    short8 a = *(const short8*)(Ap + kk);
    #pragma unroll
    for (int nj=0;nj<4;nj++){
      short8 wv = *(const short8*)(Wp[nj] + kk);
      acc[nj] = __builtin_amdgcn_mfma_f32_16x16x32_bf16(a, wv, acc[nj], 0,0,0);
    }
  }
  #pragma unroll
  for (int nj=0;nj<4;nj++)
    #pragma unroll
    for (int reg=0; reg<4; reg++){
      int rowt = kg*4 + reg;
      int col  = nj*16 + r;
      red[w*1024 + rowt*64 + col] = acc[nj][reg];
    }
  __syncthreads();
  int e0 = tid*4;
  f32x4 s = *(const f32x4*)&red[e0];
  #pragma unroll
  for (int ww=1; ww<4; ww++){
    f32x4 p = *(const f32x4*)&red[ww*1024 + e0];
    s.x += p.x; s.y += p.y; s.z += p.z; s.w += p.w;
  }
  int rowt = e0 >> 6, col = e0 & 63;
  *(f32x4*)&Cout[(size_t)(m0+rowt)*ldc + col] = s;
  if (col < 32){
    ushort4_t o = { f2bf_(s.x), f2bf_(s.y), f2bf_(s.z), f2bf_(s.w) };
    *(ushort4_t*)&dtb[(size_t)(m0+rowt)*32 + col] = o;
  }
}

// ---------------- big staged GEMM: 128(M)xBN(N) tile, BK=32, 4 waves ----------------
// BN=64 (proven R15/R20/R22 path): wave = 64x32 quadrant, 8 MFMA/step, 36KB, 4 blk/CU.
// BN=128 (R23-proven, in_proj only): wave = 64x64 quadrant, 16 MFMA/step, 48KB, 3 blk/CU
//   -- 2x MFMA-per-barrier at only -25% occupancy; pays only at in_proj's 1024-block grid
//   (R24: transferring to conv regressed -- grid/partial-traffic conditions not met).
// Ring-3, depth-2 prefetch, counted vmcnt(G), parity swizzle, XCD remap,
// nSeg K-split (seg s -> C0 + s*segBytes, bias on seg 0), uzMode, revA, per-dir bias.
template<bool OUTBF, int BN>
__global__ __launch_bounds__(256) void k_gemm_big(
    const __hip_bfloat16* __restrict__ A, int lda, int padExtra, int revA,
    const __hip_bfloat16* __restrict__ W, size_t wStride,
    void* __restrict__ C0, void* __restrict__ C1, size_t segBytes, int ldc, int coloff,
    int tiles_n, int baseBlocks, int totalBlocks, int Kc, int Kb,
    const float* __restrict__ bias0, const float* __restrict__ bias1, int act,
    const unsigned char* __restrict__ mask, int outRowSub, int dirColOff, int uzMode){
  constexpr int NJ = BN/32;                 // fragments per wave in N (2 or 4)
  constexpr int BUFE = 4096 + BN*32;        // elements per ring buffer
  __shared__ alignas(16) __hip_bfloat16 smem[3][BUFE];
  int b = blockIdx.x;
  int wg = (b & 7)*(totalBlocks >> 3) + (b >> 3);        // XCD-contiguous remap
  int seg = wg / baseBlocks;
  int bid = wg - seg*baseBlocks;
  int tn = bid % tiles_n;
  int tm = bid / tiles_n;
  int m0 = tm*128, n0 = tn*BN;
  int dir = m0 >> 12;
  int kOff = seg*Kc;
  const __hip_bfloat16* Wd = W + (size_t)dir*wStride;
  void* Cout = (void*)((char*)C0 + (size_t)seg*segBytes);
  const float* bsel = dir ? bias1 : bias0;
  const float* biasp = (bsel && seg==0) ? bsel : nullptr;

  int tid = threadIdx.x;
  int wid = tid >> 6, lane = tid & 63;
  int r = lane & 15, kg = lane >> 4;

  int sr = lane >> 2;
  int gs = (lane & 3) ^ ((sr >> 1) & 3);
  auto physrow = [&](int ar)->int{
    if (revA && ar >= 4096){
      int r2 = ar - 4096;
      return (r2 & ~1023) | (1023 - (r2 & 1023));
    }
    return ar + padExtra*(ar >> 10);
  };
  int arow0 = m0 + wid*16 + sr;
  int arow1 = arow0 + 64;
  size_t aoff0 = (size_t)physrow(arow0)*lda + kOff + gs*8;
  size_t aoff1 = (size_t)physrow(arow1)*lda + kOff + gs*8;
  size_t boffq[BN/64];
  #pragma unroll
  for (int q=0; q<BN/64; q++){
    int bcol = n0 + wid*16 + q*64 + sr;
    boffq[q] = (size_t)bcol*Kb + kOff + gs*8;
  }

  int wr = wid >> 1, wc = wid & 1;
  int xs = (kg ^ ((r >> 1) & 3))*8;
  int afrag[4], bfrag[NJ];
  #pragma unroll
  for (int mi=0; mi<4; mi++) afrag[mi] = (wr*64 + mi*16 + r)*32 + xs;
  #pragma unroll
  for (int nj=0; nj<NJ; nj++) bfrag[nj] = 4096 + (wc*(BN/2) + nj*16 + r)*32 + xs;

  f32x4 acc[4][NJ];
  #pragma unroll
  for (int mi=0;mi<4;mi++)
    #pragma unroll
    for (int nj=0;nj<NJ;nj++) acc[mi][nj] = (f32x4){0.f,0.f,0.f,0.f};

  const int nt = Kc >> 5;
  auto stage = [&](int kt, int bufi){
    __hip_bfloat16* sb = &smem[bufi][0];
    int k0 = kt*32;
    gload16((const short*)A + aoff0 + k0, sb + wid*512);
    gload16((const short*)A + aoff1 + k0, sb + (wid+4)*512);
    #pragma unroll
    for (int q=0; q<BN/64; q++)
      gload16((const short*)W + (size_t)(Wd - W) + boffq[q] + k0, sb + 4096 + (q*4 + wid)*512);
  };
  auto compute = [&](int bufi){
    const __hip_bfloat16* sb = &smem[bufi][0];
    short8 a[4], bb2[NJ];
    #pragma unroll
    for (int mi=0;mi<4;mi++) a[mi] = *(const short8*)&sb[afrag[mi]];
    #pragma unroll
    for (int nj=0;nj<NJ;nj++) bb2[nj] = *(const short8*)&sb[bfrag[nj]];
    #pragma unroll
    for (int mi=0;mi<4;mi++)
      #pragma unroll
      for (int nj=0;nj<NJ;nj++)
        acc[mi][nj] = __builtin_amdgcn_mfma_f32_16x16x32_bf16(a[mi], bb2[nj], acc[mi][nj], 0,0,0);
  };

  if (nt >= 3){
    stage(0, 0);
    stage(1, 1);
    int bi = 0;
    #pragma unroll 1
    for (int t=0; t<nt; t++){
      if (t+1 < nt){
        if constexpr (BN == 64) asm volatile("s_waitcnt vmcnt(3)" ::: "memory");
        else                    asm volatile("s_waitcnt vmcnt(4)" ::: "memory");
      } else {
        asm volatile("s_waitcnt vmcnt(0)" ::: "memory");
      }
      __builtin_amdgcn_s_barrier();
      __builtin_amdgcn_sched_barrier(0);
      if (t+2 < nt){
        int nb2 = bi + 2; if (nb2 >= 3) nb2 -= 3;
        stage(t+2, nb2);
      }
      compute(bi);
      bi = (bi+1 == 3) ? 0 : bi+1;
    }
  } else {
    for (int s=0; s<nt; s++) stage(s, s);
    asm volatile("s_waitcnt vmcnt(0)" ::: "memory");
    __builtin_amdgcn_s_barrier();
    __builtin_amdgcn_sched_barrier(0);
    for (int t=0; t<nt; t++) compute(t);
  }

  #pragma unroll
  for (int mi=0;mi<4;mi++){
    #pragma unroll
    for (int nj=0;nj<NJ;nj++){
      #pragma unroll
      for (int reg=0; reg<4; reg++){
        int row = m0 + wr*64 + mi*16 + kg*4 + reg;
        int col = n0 + wc*(BN/2) + nj*16 + r;
        float v = acc[mi][nj][reg];
        if (uzMode){
          if (col < 1024) ((__hip_bfloat16*)C0)[(size_t)row*1024 + col] = __float2bfloat16(v);
          else            ((__hip_bfloat16*)C1)[(size_t)row*1024 + (col-1024)] = __float2bfloat16(v);
          continue;
        }
        if (biasp) v += biasp[col];
        if (act == 1) v = softplus_(v);
        int row_out = row - dir*outRowSub;
        if (mask && mask[row_out]) v = 0.f;
        size_t o = (size_t)row_out*ldc + coloff + dir*dirColOff + col;
        if (OUTBF) ((__hip_bfloat16*)Cout)[o] = __float2bfloat16(v);
        else       ((float*)Cout)[o] = v;
      }
    }
  }
}

// ---------------- mamba pieces (batched: rows 0..8191, dir = row>>12) ----------------

// depthwise conv over bf16 u_pre -> bf16 ub only
__global__ void k_dwconv(const unsigned short* __restrict__ upre,
                         const float* __restrict__ cw0, const float* __restrict__ cw1,
                         const float* __restrict__ cb0, const float* __restrict__ cb1,
                         __hip_bfloat16* __restrict__ ub){
  int i = blockIdx.x*256 + threadIdx.x;     // over BL2*DI/4
  if (i >= BL2*DI/4) return;
  int d4 = i & (DI/4 - 1);
  int d = d4 << 2;
  int row = i >> 8;
  int dir = row >> 12;
  const float* cw = (dir ? cw1 : cw0) + d*4;
  const float* cb = (dir ? cb1 : cb0) + d;
  int l = row & 1023;
  int rb = row & ~1023;
  f32x4 cwv[4];
  #pragma unroll
  for (int j=0;j<4;j++) cwv[j] = *(const f32x4*)&cw[j*4];
  f32x4 acc = *(const f32x4*)cb;
  #pragma unroll
  for (int k=0;k<4;k++){
    int ll = l - 3 + k;
    if (ll >= 0){
      ushort4_t xv = *(const ushort4_t*)&upre[(size_t)(rb + ll)*DI + d];
      acc.x = __fmaf_rn(cwv[0][k], b2f_(xv.x), acc.x);
      acc.y = __fmaf_rn(cwv[1][k], b2f_(xv.y), acc.y);
      acc.z = __fmaf_rn(cwv[2][k], b2f_(xv.z), acc.z);
      acc.w = __fmaf_rn(cwv[3][k], b2f_(xv.w), acc.w);
    }
  }
  f32x4 s;
  s.x = acc.x * sigmoidf_(acc.x);
  s.y = acc.y * sigmoidf_(acc.y);
  s.z = acc.z * sigmoidf_(acc.z);
  s.w = acc.w * sigmoidf_(acc.w);
  ushort4_t o = { f2bf_(s.x), f2bf_(s.y), f2bf_(s.z), f2bf_(s.w) };
  *(ushort4_t*)((unsigned short*)ub + (size_t)i*4) = o;
}

// -------- chunked selective scan, thread-per-d, both dirs in one dispatch --------
// R27: Hp stored bf16 (f32 compute); Pp replaced by per-(chunk,d) scalar Sdv --
// comb recomputes P = exp2(Af*Sdv) with the identical op sequence (bit-identical).

__global__ __launch_bounds__(256) void k_scan_part(
    const float* __restrict__ Alog0, const float* __restrict__ Alog1,
    const unsigned short* __restrict__ dyb, const unsigned short* __restrict__ ub,
    const float* __restrict__ xdbc,
    unsigned short* __restrict__ Hp, float* __restrict__ Sdvp){
  __shared__ alignas(16) float Bsh[CLEN*16];
  int t = threadIdx.x;
  int dblk = blockIdx.x & 3;
  int c = (blockIdx.x >> 2) & (NCH-1);
  int b8 = blockIdx.x >> 7;
  const float* A_log = (b8 >> 2) ? Alog1 : Alog0;
  int d = dblk*256 + t;
  size_t blbase = (size_t)b8*LSEQ + (size_t)c*CLEN;
  if (t < CLEN*4){
    int l = t >> 2, q = t & 3;
    *(f32x4*)&Bsh[l*16 + q*4] = *(const f32x4*)&xdbc[(blbase+l)*64 + 32 + q*4];
  }
  float Af[16];
  #pragma unroll
  for (int n=0; n<16; n+=4){
    f32x4 a = *(const f32x4*)&A_log[(size_t)d*16 + n];
    Af[n]   = -__expf(a.x)*1.442695041f; Af[n+1] = -__expf(a.y)*1.442695041f;
    Af[n+2] = -__expf(a.z)*1.442695041f; Af[n+3] = -__expf(a.w)*1.442695041f;
  }
  float h[16];
  #pragma unroll
  for (int n=0;n<16;n++) h[n]=0.f;
  float Sdv = 0.f;
  const unsigned short* dyp = dyb + blbase*DI + d;
  const unsigned short* ubp = ub + blbase*DI + d;
  float dvb[2][8], uvb[2][8];
  #pragma unroll
  for (int j=0;j<8;j++){ dvb[0][j] = b2f_(dyp[(size_t)j*DI]); uvb[0][j] = b2f_(ubp[(size_t)j*DI]); }
  __syncthreads();
  #pragma unroll
  for (int g=0; g<4; g++){
    int cur = g & 1;
    if (g+1 < 4){
      int nxt = cur ^ 1;
      #pragma unroll
      for (int j=0;j<8;j++){
        size_t l = (size_t)(g+1)*8 + j;
        dvb[nxt][j] = b2f_(dyp[l*DI]); uvb[nxt][j] = b2f_(ubp[l*DI]);
      }
    }
    #pragma unroll
    for (int j=0;j<8;j++){
      int l = g*8 + j;
      float dv = dvb[cur][j], uv = uvb[cur][j];
      float duv = dv*uv;
      Sdv += dv;
      #pragma unroll
      for (int n=0;n<16;n++){
        float dA = fexp2_(dv*Af[n]);
        h[n] = __fmaf_rn(dA, h[n], duv*Bsh[l*16+n]);
      }
    }
  }
  size_t sb_ = ((size_t)(b8*NCH + c))*DI + d;
  Sdvp[sb_] = Sdv;
  size_t pb = sb_*16;
  #pragma unroll
  for (int n=0;n<16;n+=4){
    ushort4_t hv = { f2bf_(h[n]), f2bf_(h[n+1]), f2bf_(h[n+2]), f2bf_(h[n+3]) };
    *(ushort4_t*)&Hp[pb+n] = hv;
  }
}

// combine: h_in[c+1] = P[c]*h_in[c] + H[c]; P recomputed from Sdv (bit-identical to
// the old materialized Pp); h_in written bf16 into hinb. Accumulator stays f32 in reg.
__global__ void k_scan_comb(const float* __restrict__ Alog0, const float* __restrict__ Alog1,
                            const unsigned short* __restrict__ Hp, const float* __restrict__ Sdvp,
                            unsigned short* __restrict__ hinb){
  int i = blockIdx.x*256 + threadIdx.x;   // (row8k)*16 + n
  if (i >= BL2*NST) return;
  int n = i & 15, row = i >> 4;
  int b8 = row >> 10, d = row & 1023;
  const float* A_log = (b8 >> 2) ? Alog1 : Alog0;
  float Af = -__expf(A_log[(size_t)d*16 + n])*1.442695041f;
  float hin = 0.f;
  #pragma unroll
  for (int c=0;c<NCH;c++){
    size_t s = ((size_t)(b8*NCH + c))*DI + d;
    float P = fexp2_(Af * Sdvp[s]);
    float H = b2f_(Hp[s*16 + n]);
    hinb[s*16 + n] = f2bf_(hin);
    hin = __fmaf_rn(P, hin, H);
  }
}

// final pass: recompute chunk states from h_in (bf16), emit y fused with ygate -> yb (bf16)
__global__ __launch_bounds__(256) void k_scan_fin(
    const float* __restrict__ Alog0, const float* __restrict__ Alog1,
    const unsigned short* __restrict__ dyb, const unsigned short* __restrict__ ub,
    const float* __restrict__ xdbc,
    const unsigned short* __restrict__ Hin, const unsigned short* __restrict__ zb,
    const float* __restrict__ Dp0, const float* __restrict__ Dp1,
    __hip_bfloat16* __restrict__ yb){
  __shared__ alignas(16) float BCsh[CLEN*32];
  int t = threadIdx.x;
  int dblk = blockIdx.x & 3;
  int c = (blockIdx.x >> 2) & (NCH-1);
  int b8 = blockIdx.x >> 7;
  int dirb = b8 >> 2;
  const float* A_log = dirb ? Alog1 : Alog0;
  const float* Dp = dirb ? Dp1 : Dp0;
  int d = dblk*256 + t;
  size_t blbase = (size_t)b8*LSEQ + (size_t)c*CLEN;
  {
    int l = t >> 3, q = t & 7;
    *(f32x4*)&BCsh[l*32 + q*4] = *(const f32x4*)&xdbc[(blbase+l)*64 + 32 + q*4];
  }
  float Af[16];
  #pragma unroll
  for (int n=0; n<16; n+=4){
    f32x4 a = *(const f32x4*)&A_log[(size_t)d*16 + n];
    Af[n]   = -__expf(a.x)*1.442695041f; Af[n+1] = -__expf(a.y)*1.442695041f;
    Af[n+2] = -__expf(a.z)*1.442695041f; Af[n+3] = -__expf(a.w)*1.442695041f;
  }
  size_t pb = (((size_t)(b8*NCH + c))*DI + d)*16;
  float h[16];
  #pragma unroll
  for (int n=0;n<16;n+=4){
    ushort4_t hv = *(const ushort4_t*)&Hin[pb+n];
    h[n]=b2f_(hv.x); h[n+1]=b2f_(hv.y); h[n+2]=b2f_(hv.z); h[n+3]=b2f_(hv.w);
  }
  float Dd = Dp[d];
  const unsigned short* dyp = dyb + blbase*DI + d;
  const unsigned short* ubp = ub + blbase*DI + d;
  const unsigned short* zp  = zb + blbase*DI + d;
  float dvb[2][8], uvb[2][8], zvb[2][8];
  #pragma unroll
  for (int j=0;j<8;j++){
    dvb[0][j] = b2f_(dyp[(size_t)j*DI]);
    uvb[0][j] = b2f_(ubp[(size_t)j*DI]);
    zvb[0][j] = b2f_(zp[(size_t)j*DI]);
  }
  __syncthreads();
  #pragma unroll
  for (int g=0; g<4; g++){
    int cur = g & 1;
    if (g+1 < 4){
      int nxt = cur ^ 1;
      #pragma unroll
      for (int j=0;j<8;j++){
        size_t l = (size_t)(g+1)*8 + j;
        dvb[nxt][j] = b2f_(dyp[l*DI]);
        uvb[nxt][j] = b2f_(ubp[l*DI]);
        zvb[nxt][j] = b2f_(zp[l*DI]);
      }
    }
    #pragma unroll
    for (int j=0;j<8;j++){
      int l = g*8 + j;
      float dv = dvb[cur][j], uv = uvb[cur][j], zv = zvb[cur][j];
      float duv = dv*uv;
      float y = 0.f;
      #pragma unroll
      for (int n=0;n<16;n++){
        float dA = fexp2_(dv*Af[n]);
        h[n] = __fmaf_rn(dA, h[n], duv*BCsh[l*32+n]);
        y = __fmaf_rn(h[n], BCsh[l*32+16+n], y);
      }
      float gg = zv * sigmoidf_(zv);
      float out = __fmaf_rn(uv, Dd, y) * gg;
      yb[(blbase+l)*DI + d] = __float2bfloat16(out);
    }
  }
}

// ---------------- host ----------------

extern "C" void kernel_launch(void* const* d_in, const int* in_sizes, int n_in,
                              void* d_out, int out_size, void* d_ws, size_t ws_size,
                              hipStream_t stream){
  (void)in_sizes; (void)n_in; (void)out_size; (void)ws_size;
  const int*   x     = (const int*)d_in[0];
  const unsigned char* m = (const unsigned char*)d_in[2];
  const float* emb   = (const float*)d_in[3];
  const float* convw = (const float*)d_in[4];
  const float* convb = (const float*)d_in[5];
  const float* lng   = (const float*)d_in[6];
  const float* lnb   = (const float*)d_in[7];
  const float* projw = (const float*)d_in[8];
  const float* projb = (const float*)d_in[9];

  char* ws = (char*)d_ws;
  size_t off = 0;
  auto alloc = [&](size_t bytes)->char*{
    char* p = ws + off; off += (bytes + 255) & ~((size_t)255); return p;
  };
  auto wt_conv = (__hip_bfloat16*)alloc((size_t)3*CCH*CCH*5*2);
  auto w_in2  = (__hip_bfloat16*)alloc((size_t)2*2*DI*CCH*2);
  auto w_x2   = (__hip_bfloat16*)alloc((size_t)2*64*DI*2);
  auto w_dt2  = (__hip_bfloat16*)alloc((size_t)2*DI*DTR*2);
  auto w_out2 = (__hip_bfloat16*)alloc((size_t)2*CCH*DI*2);
  auto w_proj = (__hip_bfloat16*)alloc((size_t)CCH*1024*2);
  auto xpad0  = (__hip_bfloat16*)alloc((size_t)BSZ*(LSEQ+4)*CCH*2);
  auto xpad1  = (__hip_bfloat16*)alloc((size_t)BSZ*(LSEQ+4)*CCH*2);
  auto scr    = (unsigned short*)alloc((size_t)8*NCH*DI*NST*2);  // 8.4 MB: conv partial0 (bf16) / scan Hp (bf16)
  auto h_enc  = (__hip_bfloat16*)alloc((size_t)BL*CCH*2);
  auto upre   = (unsigned short*)alloc((size_t)BL2*DI*2);  // in_proj u-half, bf16
  auto zb     = (unsigned short*)alloc((size_t)BL2*DI*2);  // in_proj z-half, bf16
  auto ub2    = (__hip_bfloat16*)alloc((size_t)BL2*DI*2);  // conv'd u, bf16
  auto xdbc2  = (float*)alloc((size_t)BL2*64*4);
  auto dtb2   = (unsigned short*)alloc((size_t)BL2*DTR*2);
  auto dy2    = (unsigned short*)alloc((size_t)BL2*DI*2);  // delta bf16
  auto convp1 = (unsigned short*)alloc((size_t)BL*CCH*2);  // conv partial1 (bf16, encoder only)
  auto yb2    = (__hip_bfloat16*)alloc((size_t)BL2*DI*2);
  auto fob    = (__hip_bfloat16*)alloc((size_t)BL*DI*2);
  auto hinb   = (unsigned short*)alloc((size_t)8*NCH*DI*NST*2);  // h_in, bf16
  auto Sdvp   = (float*)alloc((size_t)8*NCH*DI*4);               // per-(chunk,d) Sdv, f32

  unsigned short* Hp = scr;

  auto nb = [](size_t n){ return (unsigned)((n + 255)/256); };

  // --- unified weight prep + embed: one dispatch (R26) ---
  {
    PrepArgs pa;
    unsigned acc = 0;
    auto put = [&](int k, const void* s, void* d, unsigned n4){
      pa.e[k].s = (const float*)s; pa.e[k].d = (unsigned short*)d;
      pa.e[k].n4 = n4; pa.e[k].acc = acc; acc += n4;
    };
    for (int dir=0; dir<2; dir++){
      int base = 10 + 9*dir;
      put(dir*4+0, d_in[base+0], (unsigned short*)w_in2  + (size_t)dir*2*DI*CCH, (2*DI*CCH)/4);
      put(dir*4+1, d_in[base+3], (unsigned short*)w_x2   + (size_t)dir*64*DI,    (64*DI)/4);
      put(dir*4+2, d_in[base+4], (unsigned short*)w_dt2  + (size_t)dir*DI*DTR,   (DI*DTR)/4);
      put(dir*4+3, d_in[base+8], (unsigned short*)w_out2 + (size_t)dir*CCH*DI,   (CCH*DI)/4);
    }
    put(8, projw, w_proj, (CCH*1024)/4);
    pa.total4 = acc;
    pa.cw = convw; pa.wt = wt_conv;
    pa.x = x; pa.emb = emb; pa.xpad0 = xpad0; pa.xpad1 = xpad1;
    pa.nbConvw = nb((size_t)3*CCH*CCH*5);
    pa.nbCast  = nb(acc);
    unsigned nbEmbed = nb((size_t)BSZ*(LSEQ+4)*CCH + BSZ*4*CCH);
    k_prep_all<<<dim3(pa.nbConvw + pa.nbCast + nbEmbed), dim3(256), 0, stream>>>(pa);
  }

  auto gemm_big = [&](const void* A, int lda, int padE, int revA, const void* W, size_t wStride,
                  void* C0, void* C1, size_t segBytes, int ldc, int coloff,
                  int M, int N, int Kc, int Kb, int nSeg,
                  const float* bias0, const float* bias1, int act,
                  const unsigned char* msk, int outRowSub, int dirColOff, bool outbf, int uzMode,
                  int bn){
    int tiles_n = N/bn;
    int baseBlocks = (M/128)*tiles_n;
    int blocks = baseBlocks * nSeg;
    if (bn == 128){
      if (outbf)
        k_gemm_big<true,128><<<dim3(blocks), dim3(256), 0, stream>>>((const __hip_bfloat16*)A, lda, padE, revA,
            (const __hip_bfloat16*)W, wStride, C0, C1, segBytes, ldc, coloff, tiles_n, baseBlocks, blocks,
            Kc, Kb, bias0, bias1, act, msk, outRowSub, dirColOff, uzMode);
      else
        k_gemm_big<false,128><<<dim3(blocks), dim3(256), 0, stream>>>((const __hip_bfloat16*)A, lda, padE, revA,
            (const __hip_bfloat16*)W, wStride, C0, C1, segBytes, ldc, coloff, tiles_n, baseBlocks, blocks,
            Kc, Kb, bias0, bias1, act, msk, outRowSub, dirColOff, uzMode);
    } else {
      if (outbf)
        k_gemm_big<true,64><<<dim3(blocks), dim3(256), 0, stream>>>((const __hip_bfloat16*)A, lda, padE, revA,
            (const __hip_bfloat16*)W, wStride, C0, C1, segBytes, ldc, coloff, tiles_n, baseBlocks, blocks,
            Kc, Kb, bias0, bias1, act, msk, outRowSub, dirColOff, uzMode);
      else
        k_gemm_big<false,64><<<dim3(blocks), dim3(256), 0, stream>>>((const __hip_bfloat16*)A, lda, padE, revA,
            (const __hip_bfloat16*)W, wStride, C0, C1, segBytes, ldc, coloff, tiles_n, baseBlocks, blocks,
            Kc, Kb, bias0, bias1, act, msk, outRowSub, dirColOff, uzMode);
    }
  };

  // --- encoder: 3x (conv-as-GEMM BN=64 2-way K-split, bf16 partials -> LN) ---
  __hip_bfloat16* xp_in = xpad0;
  __hip_bfloat16* xp_out = xpad1;
  const size_t segB_conv = (size_t)((char*)convp1 - (char*)scr);   // seg1 -> convp1
  for (int layer=0; layer<3; layer++){
    const __hip_bfloat16* wt = wt_conv + (size_t)layer*CCH*CCH*5;
    gemm_big(xp_in, CCH, 4, 0, wt, 0, scr, nullptr, segB_conv, CCH, 0, BL, CCH, 1280, 2560, 2,
             convb + layer*CCH, convb + layer*CCH, 0, nullptr, 0, 0, true, 0, 64);
    bool last = (layer==2);
    k_ln<<<dim3(BL), dim3(256), 0, stream>>>((const unsigned short*)scr, convp1,
        lng + layer*CCH, lnb + layer*CCH, m,
        last ? nullptr : xp_out, last ? h_enc : nullptr);
    __hip_bfloat16* t2 = xp_in; xp_in = xp_out; xp_out = t2;
  }

  // --- bidirectional mamba, both directions batched (rows 0..8191, dir = row>>12);
  //     dir-1 reads h_enc reversed via revA (no materialized h_rev) ---
  const float* Alog0 = (const float*)d_in[16];
  const float* Alog1 = (const float*)d_in[25];
  const float* Dp0   = (const float*)d_in[17];
  const float* Dp1   = (const float*)d_in[26];

  // in_proj: BN=128 (R23-proven: 1024 blocks, 48KB ring-3, 16 MFMA/wave/step)
  gemm_big(h_enc, CCH, 0, 1, w_in2, (size_t)2*DI*CCH, upre, zb, 0, 2*DI, 0,
           BL2, 2*DI, CCH, CCH, 1, nullptr, nullptr, 0, nullptr, 0, 0, false, 1, 128);
  k_dwconv<<<dim3(nb((size_t)BL2*DI/4)), dim3(256), 0, stream>>>(upre,
      (const float*)d_in[11], (const float*)d_in[20],
      (const float*)d_in[12], (const float*)d_in[21], ub2);
  k_gemm_ksplit<<<dim3(BL2/16), dim3(256), 0, stream>>>(ub2, DI, w_x2, (size_t)64*DI, xdbc2, 64, DI, dtb2);
  gemm_big(dtb2, DTR, 0, 0, w_dt2, (size_t)DI*DTR, dy2, nullptr, 0, DI, 0,
           BL2, DI, DTR, DTR, 1, (const float*)d_in[15], (const float*)d_in[24], 1,
           nullptr, 0, 0, true, 0, 64);
  k_scan_part<<<dim3(1024), dim3(256), 0, stream>>>(Alog0, Alog1, dy2, (const unsigned short*)ub2, xdbc2, Hp, Sdvp);
  k_scan_comb<<<dim3(nb((size_t)BL2*NST)), dim3(256), 0, stream>>>(Alog0, Alog1, Hp, Sdvp, hinb);
  k_scan_fin<<<dim3(1024), dim3(256), 0, stream>>>(Alog0, Alog1, dy2, (const unsigned short*)ub2, xdbc2, hinb, zb, Dp0, Dp1, yb2);
  gemm_big(yb2, DI, 0, 0, w_out2, (size_t)CCH*DI, fob, nullptr, 0, DI, 0,
           BL2, CCH, DI, DI, 1, nullptr, nullptr, 0, nullptr, BL, 512, true, 0, 64);

  // --- final projection + bias + mask -> d_out (f32) ---
  gemm_big(fob, DI, 0, 0, w_proj, 0, d_out, nullptr, 0, CCH, 0,
           BL, CCH, DI, DI, 1, projb, projb, 0, m, 0, 0, false, 0, 64);
}